// Round 22
// baseline (411.651 us; speedup 1.0000x reference)
//
#include <hip/hip_runtime.h>
#include <hip/hip_bf16.h>
#include <math.h>

#define BQ 2
#define LQ 2048
#define D_MODEL 1024
#define D_INNER 2048
#define D_STATE 16
#define DT_RANK 64
#define D_CONV 4
#define DEPTH 2
#define NCHUNK 64
#define CHUNK 32
#define XSPLITK 8
#define XKC (D_INNER / XSPLITK)   // 256
#define OSK 2                     // out_proj split-K

typedef __attribute__((ext_vector_type(8))) short short8v;  // 8 bf16 (4 VGPRs)
typedef __attribute__((ext_vector_type(4))) float f32x4;

__device__ __forceinline__ short f2bf(float f) {
    union { float f; unsigned u; } v; v.f = f;
    unsigned r = v.u + 0x7fffu + ((v.u >> 16) & 1u);   // RNE
    return (short)(r >> 16);
}

__device__ __forceinline__ float bf2f(unsigned short s) {
    union { unsigned u; float f; } v; v.u = ((unsigned)s) << 16;
    return v.f;
}

__device__ __forceinline__ void async16(void* lds, const void* gp) {
    __builtin_amdgcn_global_load_lds(
        (const __attribute__((address_space(1))) void*)gp,
        (__attribute__((address_space(3))) void*)lds, 16, 0, 0);
}

// dA[n] = e1^(n+1) via 3 squarings + 12 muls (valid when A[n]=(n+1)A[0])
__device__ __forceinline__ void dA_powers(float e1, float* dA) {
    float e2 = e1 * e1, e4 = e2 * e2, e8 = e4 * e4;
    dA[0] = e1;       dA[1] = e2;       dA[2] = e2 * e1;  dA[3] = e4;
    dA[4] = e4 * e1;  dA[5] = e4 * e2;  dA[6] = e4 * dA[2]; dA[7] = e8;
    dA[8] = e8 * e1;  dA[9] = e8 * e2;  dA[10] = e8 * dA[2]; dA[11] = e8 * e4;
    dA[12] = e8 * dA[4]; dA[13] = e8 * dA[5]; dA[14] = e8 * dA[6]; dA[15] = e8 * e8;
}

// ------------------------------------------------- LayerNorm (bf16 output)
__global__ __launch_bounds__(256) void layernorm_kernel(
    const float* __restrict__ x, const float* __restrict__ w,
    const float* __restrict__ b, short* __restrict__ out)
{
    __shared__ float red[8];
    int row = blockIdx.x;
    const float* xr = x + (size_t)row * D_MODEL;
    float v[4];
    float s = 0.f, sq = 0.f;
#pragma unroll
    for (int i = 0; i < 4; ++i) {
        v[i] = xr[threadIdx.x + i * 256];
        s += v[i];
        sq += v[i] * v[i];
    }
#pragma unroll
    for (int off = 32; off; off >>= 1) {
        s += __shfl_down(s, off, 64);
        sq += __shfl_down(sq, off, 64);
    }
    int wid = threadIdx.x >> 6, lane = threadIdx.x & 63;
    if (!lane) { red[wid] = s; red[4 + wid] = sq; }
    __syncthreads();
    s = red[0] + red[1] + red[2] + red[3];
    sq = red[4] + red[5] + red[6] + red[7];
    float mu = s * (1.f / D_MODEL);
    float var = sq * (1.f / D_MODEL) - mu * mu;
    float rstd = rsqrtf(var + 1e-5f);
#pragma unroll
    for (int i = 0; i < 4; ++i) {
        int c = threadIdx.x + i * 256;
        out[(size_t)row * D_MODEL + c] = f2bf((v[i] - mu) * rstd * w[c] + b[c]);
    }
}

// --------- sum OSK out_proj partials + LayerNorm (next layer input, bf16)
__global__ __launch_bounds__(256) void osum_ln_kernel(
    const float* __restrict__ P, const float* __restrict__ w,
    const float* __restrict__ b, short* __restrict__ out)
{
    __shared__ float red[8];
    int row = blockIdx.x;
    const float* p0 = P + (size_t)row * D_MODEL;
    const float* p1 = P + (size_t)BQ * LQ * D_MODEL + (size_t)row * D_MODEL;
    float v[4];
    float s = 0.f, sq = 0.f;
#pragma unroll
    for (int i = 0; i < 4; ++i) {
        int c = threadIdx.x + i * 256;
        v[i] = p0[c] + p1[c];
        s += v[i];
        sq += v[i] * v[i];
    }
#pragma unroll
    for (int off = 32; off; off >>= 1) {
        s += __shfl_down(s, off, 64);
        sq += __shfl_down(sq, off, 64);
    }
    int wid = threadIdx.x >> 6, lane = threadIdx.x & 63;
    if (!lane) { red[wid] = s; red[4 + wid] = sq; }
    __syncthreads();
    s = red[0] + red[1] + red[2] + red[3];
    sq = red[4] + red[5] + red[6] + red[7];
    float mu = s * (1.f / D_MODEL);
    float var = sq * (1.f / D_MODEL) - mu * mu;
    float rstd = rsqrtf(var + 1e-5f);
#pragma unroll
    for (int i = 0; i < 4; ++i) {
        int c = threadIdx.x + i * 256;
        out[(size_t)row * D_MODEL + c] = f2bf((v[i] - mu) * rstd * w[c] + b[c]);
    }
}

// ========== 256x256 2-phase bf16 GEMM (m230-V0 structure, T1+T4 counted vmcnt)
__global__ __launch_bounds__(512) void gemm256p2_kernel(
    const short* __restrict__ A, const short* __restrict__ W,
    short* __restrict__ C, int M, int N, int K)
{
    __shared__ __align__(16) short As[2][256 * 64];   // 2 x 32 KB
    __shared__ __align__(16) short Bs[2][256 * 64];
    const int tid = threadIdx.x;
    const int lane = tid & 63;
    const int w = tid >> 6;              // 0..7
    const int wr = w >> 2, wc = w & 3;   // 2 x 4 wave grid

    int nbx = N >> 8;
    int nwg = (M >> 8) * nbx;
    int q = nwg >> 3;                    // nwg % 8 == 0
    int wg = ((int)blockIdx.x & 7) * q + ((int)blockIdx.x >> 3);
    int bx = wg % nbx, by = wg / nbx;
    int bm = by << 8, bn = bx << 8;

    const int fr = lane & 15;
    const int kl = lane >> 4;            // 0..3
    const int lrow = lane >> 3;          // 0..7 staging row within wave slab
    const int lchunk = (lane & 7) ^ (lrow & 7);   // pre-swizzled global chunk

    f32x4 acc[8][4] = {};

    const short* Ab = A + (size_t)bm * K;
    const short* Bb = W + (size_t)bn * K;

    auto STAGE = [&](int buf, int kt) {
        int ko = kt << 6;
#pragma unroll
        for (int s = 0; s < 4; ++s) {
            int row = s * 64 + w * 8 + lrow;
            async16(&As[buf][(s * 64 + w * 8) * 64],
                    Ab + (size_t)row * K + ko + lchunk * 8);
            async16(&Bs[buf][(s * 64 + w * 8) * 64],
                    Bb + (size_t)row * K + ko + lchunk * 8);
        }
    };

    int NT = K >> 6;
    STAGE(0, 0);

    for (int t = 0; t < NT; ++t) {
        if (t + 1 < NT) {
            STAGE((t + 1) & 1, t + 1);
            asm volatile("s_waitcnt vmcnt(8)" ::: "memory");  // tile t landed
        } else {
            asm volatile("s_waitcnt vmcnt(0)" ::: "memory");
        }
        __builtin_amdgcn_s_barrier();
        __builtin_amdgcn_sched_barrier(0);
        int buf = t & 1;
        short8v af[8][2], bf[4][2];
#pragma unroll
        for (int i = 0; i < 8; ++i) {
            int rl = wr * 128 + i * 16 + fr;
            int rsw = rl & 7;
#pragma unroll
            for (int ks = 0; ks < 2; ++ks)
                af[i][ks] = *(const short8v*)&As[buf][rl * 64 + (((ks * 4 + kl) ^ rsw) * 8)];
        }
#pragma unroll
        for (int j = 0; j < 4; ++j) {
            int rl = wc * 64 + j * 16 + fr;
            int rsw = rl & 7;
#pragma unroll
            for (int ks = 0; ks < 2; ++ks)
                bf[j][ks] = *(const short8v*)&Bs[buf][rl * 64 + (((ks * 4 + kl) ^ rsw) * 8)];
        }
        asm volatile("s_waitcnt lgkmcnt(0)" ::: "memory");
        __builtin_amdgcn_sched_barrier(0);
        __builtin_amdgcn_s_setprio(1);
#pragma unroll
        for (int i = 0; i < 8; ++i)
#pragma unroll
            for (int j = 0; j < 4; ++j)
#pragma unroll
                for (int ks = 0; ks < 2; ++ks)
                    acc[i][j] = __builtin_amdgcn_mfma_f32_16x16x32_bf16(
                        af[i][ks], bf[j][ks], acc[i][j], 0, 0, 0);
        __builtin_amdgcn_s_setprio(0);
        __builtin_amdgcn_s_barrier();
        __builtin_amdgcn_sched_barrier(0);
    }

    int cr = (lane >> 4) * 4, cc = lane & 15;
#pragma unroll
    for (int i = 0; i < 8; ++i) {
        int row0 = bm + wr * 128 + i * 16 + cr;
#pragma unroll
        for (int p = 0; p < 4; ++p) {
            short* Cp = C + (size_t)(row0 + p) * N + bn + wc * 64 + cc;
#pragma unroll
            for (int j = 0; j < 4; ++j)
                Cp[j * 16] = f2bf(acc[i][j][p]);
        }
    }
}

// -------- 128x128 bf16 GEMM: BK=64, XOR-swizzled LDS, dbuf counted-vmcnt,
// -------- optional split-K (nsk>1: f32 partials at Cv + sk*M*N).
__global__ __launch_bounds__(256) void gemm_bf16_kernel(
    const short* __restrict__ A, const short* __restrict__ W,
    void* __restrict__ Cv, int M, int N, int K,
    const float* __restrict__ bias, int epilogue, int nsk)
{
    __shared__ __align__(16) short As[2][128 * 64];
    __shared__ __align__(16) short Bs[2][128 * 64];
    int tid = threadIdx.x;
    int lane = tid & 63, wv = tid >> 6;
    int nbx = N >> 7;
    int nwg = (M >> 7) * nbx;
    int ntot = nwg * nsk;
    int q = ntot >> 3;
    int wgz = ((int)blockIdx.x & 7) * q + ((int)blockIdx.x >> 3);
    int sk = wgz / nwg;
    int wg = wgz % nwg;
    int bx = wg % nbx, by = wg / nbx;
    int bm = by * 128, bn = bx * 128;
    int wr = wv >> 1, wc = wv & 1;
    int Kl = K / nsk;
    int koff = sk * Kl;

    const int fr = lane & 15;
    const int kl = lane >> 4;
    const int srow = lane >> 3;
    const int schunk = (lane & 7) ^ (srow & 7);

    f32x4 acc[4][4] = {};

    const short* Ab = A + (size_t)bm * K + koff;
    const short* Bb = W + (size_t)bn * K + koff;

    auto STAGE = [&](int buf, int kt) {
        int ko = kt << 6;
#pragma unroll
        for (int s = 0; s < 4; ++s) {
            int row = s * 32 + wv * 8 + srow;
            async16(&As[buf][s * 2048 + wv * 512], Ab + (size_t)row * K + ko + schunk * 8);
            async16(&Bs[buf][s * 2048 + wv * 512], Bb + (size_t)row * K + ko + schunk * 8);
        }
    };

    int NT = Kl >> 6;
    STAGE(0, 0);
    if (NT > 1) STAGE(1, 1);

    for (int t = 0; t < NT; ++t) {
        if (t + 1 < NT) { asm volatile("s_waitcnt vmcnt(8)" ::: "memory"); }
        else            { asm volatile("s_waitcnt vmcnt(0)" ::: "memory"); }
        __builtin_amdgcn_s_barrier();
        __builtin_amdgcn_sched_barrier(0);
        int buf = t & 1;
        short8v af[4][2], bf[4][2];
#pragma unroll
        for (int i = 0; i < 4; ++i) {
            int rl = wr * 64 + i * 16 + fr;
            int rsw = rl & 7;
#pragma unroll
            for (int ks = 0; ks < 2; ++ks)
                af[i][ks] = *(const short8v*)&As[buf][rl * 64 + (((ks * 4 + kl) ^ rsw) * 8)];
        }
#pragma unroll
        for (int j = 0; j < 4; ++j) {
            int rl = wc * 64 + j * 16 + fr;
            int rsw = rl & 7;
#pragma unroll
            for (int ks = 0; ks < 2; ++ks)
                bf[j][ks] = *(const short8v*)&Bs[buf][rl * 64 + (((ks * 4 + kl) ^ rsw) * 8)];
        }
        asm volatile("s_waitcnt lgkmcnt(0)" ::: "memory");
        __builtin_amdgcn_sched_barrier(0);
        __builtin_amdgcn_s_setprio(1);
#pragma unroll
        for (int i = 0; i < 4; ++i)
#pragma unroll
            for (int j = 0; j < 4; ++j)
#pragma unroll
                for (int ks = 0; ks < 2; ++ks)
                    acc[i][j] = __builtin_amdgcn_mfma_f32_16x16x32_bf16(
                        af[i][ks], bf[j][ks], acc[i][j], 0, 0, 0);
        __builtin_amdgcn_s_setprio(0);
        __builtin_amdgcn_s_barrier();
        __builtin_amdgcn_sched_barrier(0);
        if (t + 2 < NT) STAGE(buf, t + 2);
    }

    int cr = (lane >> 4) * 4, cc = lane & 15;
    size_t skoff = (size_t)sk * M * N;
#pragma unroll
    for (int i = 0; i < 4; ++i)
#pragma unroll
        for (int p = 0; p < 4; ++p) {
            int row = bm + wr * 64 + i * 16 + cr + p;
#pragma unroll
            for (int j = 0; j < 4; ++j) {
                int col = bn + wc * 64 + cc + j * 16;
                float v = acc[i][j][p];
                if (epilogue == 2)
                    ((short*)Cv)[(size_t)row * N + col] = f2bf(v);
                else
                    ((float*)Cv)[skoff + (size_t)row * N + col] = v;
            }
        }
}

// ---------------- sum OSK split-K partials -> f32 dst (final layer)
__global__ __launch_bounds__(256) void osum_kernel(
    const float* __restrict__ P, float* __restrict__ out)
{
    size_t i = ((size_t)blockIdx.x * 256 + threadIdx.x) * 4;
    float4 a = *(const float4*)(P + i);
    float4 b = *(const float4*)(P + (size_t)BQ * LQ * D_MODEL + i);
    a.x += b.x; a.y += b.y; a.z += b.z; a.w += b.w;
    *(float4*)(out + i) = a;
}

// ---------- dt_proj: K=64 direct-register MFMA, no LDS, no barriers.
__global__ __launch_bounds__(256) void dtproj_kernel(
    const short* __restrict__ A, const short* __restrict__ W,
    const float* __restrict__ bias, short* __restrict__ Out)
{
    int lane = threadIdx.x & 63, w = threadIdx.x >> 6;
    int m0 = blockIdx.y * 64 + w * 16;
    int bn = blockIdx.x * 128;
    int fr = lane & 15, fk = (lane >> 4) * 8;
    const short* Ap = A + (size_t)(m0 + fr) * DT_RANK + fk;
    short8v a0 = *(const short8v*)(Ap);
    short8v a1 = *(const short8v*)(Ap + 32);
    f32x4 acc[8] = {};
#pragma unroll
    for (int j = 0; j < 8; ++j) {
        const short* Wp = W + (size_t)(bn + j * 16 + fr) * DT_RANK + fk;
        short8v b0 = *(const short8v*)(Wp);
        short8v b1 = *(const short8v*)(Wp + 32);
        acc[j] = __builtin_amdgcn_mfma_f32_16x16x32_bf16(a0, b0, acc[j], 0, 0, 0);
        acc[j] = __builtin_amdgcn_mfma_f32_16x16x32_bf16(a1, b1, acc[j], 0, 0, 0);
    }
    int cr = (lane >> 4) * 4, cc = lane & 15;
#pragma unroll
    for (int j = 0; j < 8; ++j) {
        int col = bn + j * 16 + cc;
        float bv = bias[col];
#pragma unroll
        for (int p = 0; p < 4; ++p) {
            float v = acc[j][p] + bv;
            v = (v > 20.f) ? v : __logf(1.f + __expf(v));
            Out[(size_t)(m0 + cr + p) * D_INNER + col] = f2bf(v);
        }
    }
}

// ------------------------- x_proj: tall-skinny split-K bf16 MFMA, no LDS
__global__ __launch_bounds__(256) void xproj_kernel(
    const short* __restrict__ A, const short* __restrict__ W,
    float* __restrict__ Xpart)
{
    int lane = threadIdx.x & 63, wv = threadIdx.x >> 6;
    int sk = blockIdx.x;
    int m0 = blockIdx.y * 64 + wv * 16;
    int fr = lane & 15, fk = (lane >> 4) * 8;
    const short* Ap = A + (size_t)(m0 + fr) * D_INNER + sk * XKC + fk;
    const short* Wp = W + (size_t)fr * D_INNER + sk * XKC + fk;
    f32x4 acc[6] = {};
    for (int k = 0; k < XKC; k += 32) {
        short8v af = *(const short8v*)(Ap + k);
#pragma unroll
        for (int j = 0; j < 6; ++j) {
            short8v bf = *(const short8v*)(Wp + (size_t)j * 16 * D_INNER + k);
            acc[j] = __builtin_amdgcn_mfma_f32_16x16x32_bf16(af, bf, acc[j], 0, 0, 0);
        }
    }
    int cr = (lane >> 4) * 4, cc = lane & 15;
    float* Op = Xpart + ((size_t)sk * (BQ * LQ) + m0 + cr) * 96 + cc;
#pragma unroll
    for (int j = 0; j < 6; ++j)
#pragma unroll
        for (int p = 0; p < 4; ++p)
            Op[(size_t)p * 96 + j * 16] = acc[j][p];
}

// reduce split-K partials -> xdbl f32; also emit compact bf16 dt_r [BL][64]
__global__ __launch_bounds__(256) void xreduce_kernel(
    const float* __restrict__ Xpart, float* __restrict__ xdbl,
    short* __restrict__ dtr)
{
    size_t i = (size_t)blockIdx.x * 256 + threadIdx.x;
    float s = 0.f;
#pragma unroll
    for (int sk = 0; sk < XSPLITK; ++sk)
        s += Xpart[(size_t)sk * ((size_t)BQ * LQ * 96) + i];
    xdbl[i] = s;
    int col = (int)(i % 96);
    if (col < DT_RANK)
        dtr[(i / 96) * DT_RANK + col] = f2bf(s);
}

// --------------------------- causal conv + SiLU, 2 channels/thread
__global__ __launch_bounds__(256) void conv_silu_kernel(
    const unsigned short* __restrict__ uz, short* __restrict__ outb,
    const float* __restrict__ w, const float* __restrict__ bias)
{
    int idx = blockIdx.x * 256 + threadIdx.x;
    int e0 = idx * 2;
    int c = e0 & (D_INNER - 1);
    int bl = e0 / D_INNER;
    int l = bl & (LQ - 1);
    int b = bl / LQ;
    float acc0 = bias[c], acc1 = bias[c + 1];
    float w0[D_CONV], w1[D_CONV];
#pragma unroll
    for (int k = 0; k < D_CONV; ++k) {
        w0[k] = w[c * D_CONV + k];
        w1[k] = w[(c + 1) * D_CONV + k];
    }
#pragma unroll
    for (int k = 0; k < D_CONV; ++k) {
        int ls = l - (D_CONV - 1) + k;
        if (ls >= 0) {
            unsigned v = *(const unsigned*)&uz[((size_t)b * LQ + ls) * (2 * D_INNER) + c];
            acc0 += bf2f((unsigned short)(v & 0xffff)) * w0[k];
            acc1 += bf2f((unsigned short)(v >> 16)) * w1[k];
        }
    }
    float v0 = acc0 / (1.f + __expf(-acc0));
    float v1 = acc1 / (1.f + __expf(-acc1));
    unsigned o = (unsigned)(unsigned short)f2bf(v0) |
                 ((unsigned)(unsigned short)f2bf(v1) << 16);
    *(unsigned*)&outb[e0] = o;
}

// -------------------------------------------- selective scan, chunked 3-phase
// phase 1: async-LDS-staged u/dt (T14), dA-powers fast path; f32 Fbuf.
__global__ __launch_bounds__(256) void scan_phase1_kernel(
    const unsigned short* __restrict__ u, const unsigned short* __restrict__ dt,
    const float* __restrict__ xdbl, const float* __restrict__ A_log,
    float* __restrict__ dtsumb, float* __restrict__ Fbuf)
{
    __shared__ float S[CHUNK][D_STATE];
    __shared__ __align__(16) unsigned short Ub[2][8][256];
    __shared__ __align__(16) unsigned short Db[2][8][256];
    int t = threadIdx.x;
    int d0 = blockIdx.x * 256;
    int d = d0 + t;
    int c = blockIdx.y;
    int b = blockIdx.z;
    int l0 = c * CHUNK;
    {
        int row = t >> 3, cc2 = (t & 7) * 2;
        const float* src = xdbl + ((size_t)(b * LQ + l0 + row)) * 96 + DT_RANK + cc2;
        *(float2*)&S[row][cc2] = *(const float2*)src;
    }
    const int w = t >> 6, lane = t & 63;
    const int srw = 2 * w + (lane >> 5);
    const int scl = (lane & 31) * 8;
    const unsigned short* ubp = u  + ((size_t)b * LQ + l0) * D_INNER + d0;
    const unsigned short* dbp = dt + ((size_t)b * LQ + l0) * D_INNER + d0;
    auto STAGE1 = [&](int buf, int lb) {
        async16(&Ub[buf][2 * w][0], ubp + (size_t)(lb + srw) * D_INNER + scl);
        async16(&Db[buf][2 * w][0], dbp + (size_t)(lb + srw) * D_INNER + scl);
    };
    STAGE1(0, 0);

    float A[D_STATE], h[D_STATE];
    {
        const float4* ap = (const float4*)(A_log + (size_t)d * D_STATE);
#pragma unroll
        for (int g = 0; g < 4; ++g) {
            float4 a = ap[g];
            A[g*4+0] = -__expf(a.x); A[g*4+1] = -__expf(a.y);
            A[g*4+2] = -__expf(a.z); A[g*4+3] = -__expf(a.w);
        }
    }
    bool pf = true;
#pragma unroll
    for (int n = 1; n < D_STATE; ++n)
        pf = pf && (fabsf(A[n] - (float)(n + 1) * A[0]) <= 1e-4f * (float)(n + 1));
#pragma unroll
    for (int n = 0; n < D_STATE; ++n) h[n] = 0.f;
    float dtsum = 0.f;
    float A0 = A[0];
    asm volatile("s_waitcnt lgkmcnt(0)" ::: "memory");

    for (int bb = 0; bb < CHUNK / 8; ++bb) {
        int buf = bb & 1;
        if (bb + 1 < CHUNK / 8) {
            STAGE1(buf ^ 1, (bb + 1) * 8);
            asm volatile("s_waitcnt vmcnt(2)" ::: "memory");
        } else {
            asm volatile("s_waitcnt vmcnt(0)" ::: "memory");
        }
        __builtin_amdgcn_s_barrier();
        __builtin_amdgcn_sched_barrier(0);
        float uvv[8], dtvv[8];
#pragma unroll
        for (int i = 0; i < 8; ++i) {
            uvv[i]  = bf2f(Ub[buf][i][t]);
            dtvv[i] = bf2f(Db[buf][i][t]);
        }
        if (pf) {
#pragma unroll
            for (int i = 0; i < 8; ++i) {
                int l = bb * 8 + i;
                float dtv = dtvv[i];
                float du = dtv * uvv[i];
                dtsum += dtv;
                float dA[D_STATE];
                dA_powers(__expf(dtv * A0), dA);
#pragma unroll
                for (int n4 = 0; n4 < D_STATE; n4 += 4) {
                    float4 Bv = *(const float4*)&S[l][n4];
                    float bb2[4] = {Bv.x, Bv.y, Bv.z, Bv.w};
#pragma unroll
                    for (int k = 0; k < 4; ++k) {
                        int n = n4 + k;
                        h[n] = dA[n] * h[n] + du * bb2[k];
                    }
                }
            }
        } else {
#pragma unroll
            for (int i = 0; i < 8; ++i) {
                int l = bb * 8 + i;
                float dtv = dtvv[i];
                float du = dtv * uvv[i];
                dtsum += dtv;
#pragma unroll
                for (int n4 = 0; n4 < D_STATE; n4 += 4) {
                    float4 Bv = *(const float4*)&S[l][n4];
                    float bb2[4] = {Bv.x, Bv.y, Bv.z, Bv.w};
#pragma unroll
                    for (int k = 0; k < 4; ++k) {
                        int n = n4 + k;
                        float dA = __expf(dtv * A[n]);
                        h[n] = dA * h[n] + du * bb2[k];
                    }
                }
            }
        }
        __builtin_amdgcn_s_barrier();
        __builtin_amdgcn_sched_barrier(0);
    }
    dtsumb[(size_t)(b * NCHUNK + c) * D_INNER + d] = dtsum;
    size_t base = ((size_t)(b * NCHUNK + c) * D_STATE) * D_INNER + d;
#pragma unroll
    for (int n = 0; n < D_STATE; ++n)
        Fbuf[base + (size_t)n * D_INNER] = h[n];
}

// phase 2: sequential combine; P = exp(A * dtsum) recomputed here
__global__ __launch_bounds__(256) void scan_phase2_kernel(
    const float* __restrict__ dtsumb, const float* __restrict__ A_log,
    float* __restrict__ Fbuf)
{
    int d = blockIdx.x * 256 + threadIdx.x;
    int n = blockIdx.y;
    int b = blockIdx.z;
    float A = -__expf(A_log[(size_t)d * D_STATE + n]);
    float hinit = 0.f;
    for (int c = 0; c < NCHUNK; ++c) {
        size_t idx = ((size_t)(b * NCHUNK + c) * D_STATE + n) * D_INNER + d;
        float F = Fbuf[idx];
        float P = __expf(A * dtsumb[(size_t)(b * NCHUNK + c) * D_INNER + d]);
        Fbuf[idx] = hinit;
        hinit = P * hinit + F;
    }
}

// phase 3: async-LDS-staged u/dt/z (T14), B+C XOR-swizzled, dA-powers,
// fused gate, bf16 out; f32 Hinit.
__global__ __launch_bounds__(256) void scan_phase3_kernel(
    const unsigned short* __restrict__ u, const unsigned short* __restrict__ dt,
    const float* __restrict__ xdbl, const float* __restrict__ A_log,
    const float* __restrict__ Dp, const float* __restrict__ Hinit,
    const unsigned short* __restrict__ uz, short* __restrict__ yout)
{
    __shared__ float S[CHUNK][32];
    __shared__ __align__(16) unsigned short Ub[2][8][256];
    __shared__ __align__(16) unsigned short Db[2][8][256];
    __shared__ __align__(16) unsigned short Zb[2][8][256];
    int t = threadIdx.x;
    int d0 = blockIdx.x * 256;
    int d = d0 + t;
    int c = blockIdx.y;
    int b = blockIdx.z;
    int l0 = c * CHUNK;
    {
        int row = t >> 3, cg = (t & 7) * 4;
        const float* src = xdbl + ((size_t)(b * LQ + l0 + row)) * 96 + DT_RANK + cg;
        *(float4*)&S[row][cg ^ ((row & 7) << 2)] = *(const float4*)src;
    }
    const int w = t >> 6, lane = t & 63;
    const int srw = 2 * w + (lane >> 5);
    const int scl = (lane & 31) * 8;
    const unsigned short* ubp = u  + ((size_t)b * LQ + l0) * D_INNER + d0;
    const unsigned short* dbp = dt + ((size_t)b * LQ + l0) * D_INNER + d0;
    const unsigned short* zbp = uz + ((size_t)b * LQ + l0) * (2 * D_INNER) + D_INNER + d0;
    auto STAGE3 = [&](int buf, int lb) {
        async16(&Ub[buf][2 * w][0], ubp + (size_t)(lb + srw) * D_INNER + scl);
        async16(&Db[buf][2 * w][0], dbp + (size_t)(lb + srw) * D_INNER + scl);
        async16(&Zb[buf][2 * w][0], zbp + (size_t)(lb + srw) * (2 * D_INNER) + scl);
    };
    STAGE3(0, 0);

    float A[D_STATE], h[D_STATE];
    {
        const float4* ap = (const float4*)(A_log + (size_t)d * D_STATE);
#pragma unroll
        for (int g = 0; g < 4; ++g) {
            float4 a = ap[g];
            A[g*4+0] = -__expf(a.x); A[g*4+1] = -__expf(a.y);
            A[g*4+2] = -__expf(a.z); A[g*4+3] = -__expf(a.w);
        }
    }
    bool pf = true;
#pragma unroll
    for (int n = 1; n < D_STATE; ++n)
        pf = pf && (fabsf(A[n] - (float)(n + 1) * A[0]) <= 1e-4f * (float)(n + 1));
    size_t base = ((size_t)(b * NCHUNK + c) * D_STATE) * D_INNER + d;
#pragma unroll
    for (int n = 0; n < D_STATE; ++n)
        h[n] = Hinit[base + (size_t)n * D_INNER];
    float Dd = Dp[d];
    float A0 = A[0];
    short* yp = yout + ((size_t)b * LQ + l0) * D_INNER + d;
    asm volatile("s_waitcnt lgkmcnt(0)" ::: "memory");

    for (int bb = 0; bb < CHUNK / 8; ++bb) {
        int buf = bb & 1;
        if (bb + 1 < CHUNK / 8) {
            STAGE3(buf ^ 1, (bb + 1) * 8);
            asm volatile("s_waitcnt vmcnt(3)" ::: "memory");
        } else {
            asm volatile("s_waitcnt vmcnt(0)" ::: "memory");
        }
        __builtin_amdgcn_s_barrier();
        __builtin_amdgcn_sched_barrier(0);
        float uvv[8], dtvv[8], zvv[8];
#pragma unroll
        for (int i = 0; i < 8; ++i) {
            uvv[i]  = bf2f(Ub[buf][i][t]);
            dtvv[i] = bf2f(Db[buf][i][t]);
            zvv[i]  = bf2f(Zb[buf][i][t]);
        }
        if (pf) {
#pragma unroll
            for (int i = 0; i < 8; ++i) {
                int l = bb * 8 + i;
                float dtv = dtvv[i];
                float du = dtv * uvv[i];
                float acc = 0.f;
                int sw = (l & 7) << 2;
                float dA[D_STATE];
                dA_powers(__expf(dtv * A0), dA);
#pragma unroll
                for (int n4 = 0; n4 < D_STATE; n4 += 4) {
                    float4 Bv = *(const float4*)&S[l][n4 ^ sw];
                    float4 Cv = *(const float4*)&S[l][(16 + n4) ^ sw];
                    float bb2[4] = {Bv.x, Bv.y, Bv.z, Bv.w};
                    float cc2[4] = {Cv.x, Cv.y, Cv.z, Cv.w};
#pragma unroll
                    for (int k = 0; k < 4; ++k) {
                        int n = n4 + k;
                        h[n] = dA[n] * h[n] + du * bb2[k];
                        acc += h[n] * cc2[k];
                    }
                }
                float y = acc + uvv[i] * Dd;
                float zv = zvv[i];
                float g = zv / (1.f + __expf(-zv));
                yp[(size_t)l * D_INNER] = f2bf(y * g);
            }
        } else {
#pragma unroll
            for (int i = 0; i < 8; ++i) {
                int l = bb * 8 + i;
                float dtv = dtvv[i];
                float du = dtv * uvv[i];
                float acc = 0.f;
                int sw = (l & 7) << 2;
#pragma unroll
                for (int n4 = 0; n4 < D_STATE; n4 += 4) {
                    float4 Bv = *(const float4*)&S[l][n4 ^ sw];
                    float4 Cv = *(const float4*)&S[l][(16 + n4) ^ sw];
                    float bb2[4] = {Bv.x, Bv.y, Bv.z, Bv.w};
                    float cc2[4] = {Cv.x, Cv.y, Cv.z, Cv.w};
#pragma unroll
                    for (int k = 0; k < 4; ++k) {
                        int n = n4 + k;
                        float dA = __expf(dtv * A[n]);
                        h[n] = dA * h[n] + du * bb2[k];
                        acc += h[n] * cc2[k];
                    }
                }
                float y = acc + uvv[i] * Dd;
                float zv = zvv[i];
                float g = zv / (1.f + __expf(-zv));
                yp[(size_t)l * D_INNER] = f2bf(y * g);
            }
        }
        __builtin_amdgcn_s_barrier();
        __builtin_amdgcn_sched_barrier(0);
    }
}

// --------------- all 4 weight tensors -> bf16 in ONE launch
__global__ __launch_bounds__(256) void convert_all_kernel(
    const float* __restrict__ w_in, const float* __restrict__ w_out,
    const float* __restrict__ w_xp, const float* __restrict__ w_dt,
    short* __restrict__ wbuf)
{
    const int IN_B  = (2 * D_INNER * D_MODEL) / 1024;
    const int OUT_B = (D_MODEL * D_INNER) / 1024;
    const int XP_B  = (96 * D_INNER) / 1024;
    int blk = blockIdx.x;
    const float* src; short* dst;
    if (blk < IN_B)                 { src = w_in;  dst = wbuf; }
    else if (blk < IN_B + OUT_B)    { src = w_out; dst = wbuf + 2 * D_INNER * D_MODEL; blk -= IN_B; }
    else if (blk < IN_B + OUT_B + XP_B) { src = w_xp; dst = wbuf + 2 * D_INNER * D_MODEL + D_MODEL * D_INNER; blk -= IN_B + OUT_B; }
    else { src = w_dt; dst = wbuf + 2 * D_INNER * D_MODEL + D_MODEL * D_INNER + 96 * D_INNER; blk -= IN_B + OUT_B + XP_B; }
    int i = blk * 1024 + threadIdx.x * 4;
    float4 v = *(const float4*)(src + i);
    short4 o = make_short4(f2bf(v.x), f2bf(v.y), f2bf(v.z), f2bf(v.w));
    *(short4*)(dst + i) = o;
}

// ---------------------------------------------------------------- launcher
extern "C" void kernel_launch(void* const* d_in, const int* in_sizes, int n_in,
                              void* d_out, int out_size, void* d_ws, size_t ws_size,
                              hipStream_t stream)
{
    const float* x        = (const float*)d_in[0];
    const float* norm_w   = (const float*)d_in[2];
    const float* norm_b   = (const float*)d_in[3];
    const float* in_proj  = (const float*)d_in[4];
    const float* conv_w   = (const float*)d_in[5];
    const float* conv_b   = (const float*)d_in[6];
    const float* x_proj   = (const float*)d_in[7];
    const float* dt_proj  = (const float*)d_in[8];
    const float* dt_projb = (const float*)d_in[9];
    const float* A_log    = (const float*)d_in[10];
    const float* Dp       = (const float*)d_in[11];
    const float* out_proj = (const float*)d_in[12];
    float* out = (float*)d_out;
    float* ws  = (float*)d_ws;

    const size_t BL   = (size_t)BQ * LQ;            // 4096
    const size_t BLDM = BL * D_MODEL;
    const size_t BLDI = BL * D_INNER;
    const int IN_W  = 2 * D_INNER * D_MODEL;
    const int OUT_W = D_MODEL * D_INNER;
    const int XP_W  = 96 * D_INNER;
    const int DT_W  = D_INNER * DT_RANK;
    const int CV_BLOCKS = (IN_W + OUT_W + XP_W + DT_W) / 1024;

    size_t o = 0;
    short* hnb   = (short*)(ws + o); o += BLDM / 2;
    short* uzb   = (short*)(ws + o); o += BL * 2 * D_INNER / 2;
    short* dtb   = (short*)(ws + o); o += BLDI / 2;
    float* xdbl  = ws + o; o += BL * 96;
    float* Xpart = ws + o; o += (size_t)XSPLITK * BL * 96;
    float* Fbuf  = ws + o; o += (size_t)BQ * NCHUNK * D_STATE * D_INNER;
    float* dtsumb = ws + o; o += (size_t)BQ * NCHUNK * D_INNER;
    short* ucx   = (short*)(ws + o); o += BLDI / 2;
    short* dtr   = (short*)(ws + o); o += BL * DT_RANK / 2;
    float* Opart = ws + o; o += (size_t)OSK * BLDM;
    short* wbuf  = (short*)(ws + o);
    o += (size_t)(IN_W + OUT_W + XP_W + DT_W + 1) / 2;

    for (int layer = 0; layer < DEPTH; ++layer) {
        if (layer == 0)
            layernorm_kernel<<<(int)BL, 256, 0, stream>>>(
                x, norm_w, norm_b, hnb);

        convert_all_kernel<<<CV_BLOCKS, 256, 0, stream>>>(
            in_proj + (size_t)layer * IN_W, out_proj + (size_t)layer * OUT_W,
            x_proj + (size_t)layer * XP_W, dt_proj + (size_t)layer * DT_W, wbuf);

        // fused in_proj: M=4096, N=4096, K=1024 -> 2-phase 256^2 counted-vmcnt
        gemm256p2_kernel<<<(int)(BL / 256) * (2 * D_INNER / 256), 512, 0, stream>>>(
            hnb, wbuf, uzb, (int)BL, 2 * D_INNER, D_MODEL);

        conv_silu_kernel<<<(int)(BLDI / 512), 256, 0, stream>>>(
            (const unsigned short*)uzb, ucx,
            conv_w + (size_t)layer * D_INNER * D_CONV,
            conv_b + (size_t)layer * D_INNER);

        xproj_kernel<<<dim3(XSPLITK, BL / 64), 256, 0, stream>>>(
            ucx, wbuf + IN_W + OUT_W, Xpart);
        xreduce_kernel<<<(int)(BL * 96 / 256), 256, 0, stream>>>(Xpart, xdbl, dtr);

        dtproj_kernel<<<dim3(D_INNER / 128, BL / 64), 256, 0, stream>>>(
            dtr, wbuf + IN_W + OUT_W + XP_W,
            dt_projb + (size_t)layer * D_INNER, dtb);

        const float* Al = A_log + (size_t)layer * D_INNER * D_STATE;
        scan_phase1_kernel<<<dim3(D_INNER / 256, NCHUNK, BQ), 256, 0, stream>>>(
            (const unsigned short*)ucx, (const unsigned short*)dtb, xdbl, Al,
            dtsumb, Fbuf);
        scan_phase2_kernel<<<dim3(D_INNER / 256, D_STATE, BQ), 256, 0, stream>>>(
            dtsumb, Al, Fbuf);
        scan_phase3_kernel<<<dim3(D_INNER / 256, NCHUNK, BQ), 256, 0, stream>>>(
            (const unsigned short*)ucx, (const unsigned short*)dtb, xdbl, Al,
            Dp + (size_t)layer * D_INNER, Fbuf,
            (const unsigned short*)uzb, (short*)ucx);

        gemm_bf16_kernel<<<(int)(BL / 128) * (D_MODEL / 128) * OSK, 256, 0, stream>>>(
            ucx, wbuf + IN_W, Opart, (int)BL, D_MODEL, D_INNER, nullptr, 0, OSK);

        if (layer == DEPTH - 1)
            osum_kernel<<<(int)(BLDM / 1024), 256, 0, stream>>>(Opart, out);
        else
            osum_ln_kernel<<<(int)BL, 256, 0, stream>>>(
                Opart, norm_w + (size_t)(layer + 1) * D_MODEL,
                norm_b + (size_t)(layer + 1) * D_MODEL, hnb);
    }
}

// Round 23
// 407.195 us; speedup vs baseline: 1.0109x; 1.0109x over previous
//
#include <hip/hip_runtime.h>
#include <hip/hip_bf16.h>
#include <math.h>

#define BQ 2
#define LQ 2048
#define D_MODEL 1024
#define D_INNER 2048
#define D_STATE 16
#define DT_RANK 64
#define D_CONV 4
#define DEPTH 2
#define NCHUNK 64
#define CHUNK 32
#define XSPLITK 8
#define XKC (D_INNER / XSPLITK)   // 256
#define OSK 2                     // out_proj split-K

typedef __attribute__((ext_vector_type(8))) short short8v;  // 8 bf16 (4 VGPRs)
typedef __attribute__((ext_vector_type(4))) float f32x4;

__device__ __forceinline__ short f2bf(float f) {
    union { float f; unsigned u; } v; v.f = f;
    unsigned r = v.u + 0x7fffu + ((v.u >> 16) & 1u);   // RNE
    return (short)(r >> 16);
}

__device__ __forceinline__ float bf2f(unsigned short s) {
    union { unsigned u; float f; } v; v.u = ((unsigned)s) << 16;
    return v.f;
}

__device__ __forceinline__ void async16(void* lds, const void* gp) {
    __builtin_amdgcn_global_load_lds(
        (const __attribute__((address_space(1))) void*)gp,
        (__attribute__((address_space(3))) void*)lds, 16, 0, 0);
}

// dA[n] = e1^(n+1) via 3 squarings + 12 muls (valid when A[n]=(n+1)A[0])
__device__ __forceinline__ void dA_powers(float e1, float* dA) {
    float e2 = e1 * e1, e4 = e2 * e2, e8 = e4 * e4;
    dA[0] = e1;       dA[1] = e2;       dA[2] = e2 * e1;  dA[3] = e4;
    dA[4] = e4 * e1;  dA[5] = e4 * e2;  dA[6] = e4 * dA[2]; dA[7] = e8;
    dA[8] = e8 * e1;  dA[9] = e8 * e2;  dA[10] = e8 * dA[2]; dA[11] = e8 * e4;
    dA[12] = e8 * dA[4]; dA[13] = e8 * dA[5]; dA[14] = e8 * dA[6]; dA[15] = e8 * e8;
}

// ------------------------------------------------- LayerNorm (bf16 output)
__global__ __launch_bounds__(256) void layernorm_kernel(
    const float* __restrict__ x, const float* __restrict__ w,
    const float* __restrict__ b, short* __restrict__ out)
{
    __shared__ float red[8];
    int row = blockIdx.x;
    const float* xr = x + (size_t)row * D_MODEL;
    float v[4];
    float s = 0.f, sq = 0.f;
#pragma unroll
    for (int i = 0; i < 4; ++i) {
        v[i] = xr[threadIdx.x + i * 256];
        s += v[i];
        sq += v[i] * v[i];
    }
#pragma unroll
    for (int off = 32; off; off >>= 1) {
        s += __shfl_down(s, off, 64);
        sq += __shfl_down(sq, off, 64);
    }
    int wid = threadIdx.x >> 6, lane = threadIdx.x & 63;
    if (!lane) { red[wid] = s; red[4 + wid] = sq; }
    __syncthreads();
    s = red[0] + red[1] + red[2] + red[3];
    sq = red[4] + red[5] + red[6] + red[7];
    float mu = s * (1.f / D_MODEL);
    float var = sq * (1.f / D_MODEL) - mu * mu;
    float rstd = rsqrtf(var + 1e-5f);
#pragma unroll
    for (int i = 0; i < 4; ++i) {
        int c = threadIdx.x + i * 256;
        out[(size_t)row * D_MODEL + c] = f2bf((v[i] - mu) * rstd * w[c] + b[c]);
    }
}

// --------- sum OSK out_proj partials + LayerNorm (next layer input, bf16)
__global__ __launch_bounds__(256) void osum_ln_kernel(
    const float* __restrict__ P, const float* __restrict__ w,
    const float* __restrict__ b, short* __restrict__ out)
{
    __shared__ float red[8];
    int row = blockIdx.x;
    const float* p0 = P + (size_t)row * D_MODEL;
    const float* p1 = P + (size_t)BQ * LQ * D_MODEL + (size_t)row * D_MODEL;
    float v[4];
    float s = 0.f, sq = 0.f;
#pragma unroll
    for (int i = 0; i < 4; ++i) {
        int c = threadIdx.x + i * 256;
        v[i] = p0[c] + p1[c];
        s += v[i];
        sq += v[i] * v[i];
    }
#pragma unroll
    for (int off = 32; off; off >>= 1) {
        s += __shfl_down(s, off, 64);
        sq += __shfl_down(sq, off, 64);
    }
    int wid = threadIdx.x >> 6, lane = threadIdx.x & 63;
    if (!lane) { red[wid] = s; red[4 + wid] = sq; }
    __syncthreads();
    s = red[0] + red[1] + red[2] + red[3];
    sq = red[4] + red[5] + red[6] + red[7];
    float mu = s * (1.f / D_MODEL);
    float var = sq * (1.f / D_MODEL) - mu * mu;
    float rstd = rsqrtf(var + 1e-5f);
#pragma unroll
    for (int i = 0; i < 4; ++i) {
        int c = threadIdx.x + i * 256;
        out[(size_t)row * D_MODEL + c] = f2bf((v[i] - mu) * rstd * w[c] + b[c]);
    }
}

// =================== 256x256 8-phase bf16 GEMM (T1+T2+T3+T4+T5) ===========
__global__ __launch_bounds__(512) void gemm256_bf16_kernel(
    const short* __restrict__ A, const short* __restrict__ W,
    short* __restrict__ C, int M, int N, int K)
{
    __shared__ __align__(16) short lds[65536];   // 128 KB
    const int tid = threadIdx.x;
    const int lane = tid & 63;
    const int w = tid >> 6;              // 0..7
    const int wr = w >> 2, wc = w & 3;   // 2 x 4 wave grid

    int nbx = N >> 8;
    int nwg = (M >> 8) * nbx;
    int q = nwg >> 3;                    // nwg % 8 == 0
    int wg = ((int)blockIdx.x & 7) * q + ((int)blockIdx.x >> 3);
    int bx = wg % nbx, by = wg / nbx;
    int bm = by << 8, bn = bx << 8;

    const int fr = lane & 15;
    const int kl = lane >> 4;
    const int srow = lane >> 3;
    const int schunk = (lane & 7) ^ (srow & 7);

    f32x4 acc[8][4] = {};
    short8v af[4][2], bfA[2][2], bfB[2][2];

    auto STAGE = [&](int isA, int buf, int half, int kt) {
        const short* gp = isA ? A : W;
        int tile0 = isA ? bm : bn;
        int base = (isA ? 0 : 32768) + (buf * 2 + half) * 8192;
        int ko = kt << 6;
#pragma unroll
        for (int s = 0; s < 2; ++s) {
            int row = half * 128 + s * 64 + w * 8 + srow;
            const short* src = gp + (size_t)(tile0 + row) * K + ko + schunk * 8;
            async16(&lds[base + s * 4096 + w * 512], src);
        }
    };

    auto LOAD_A = [&](int buf, int mh) {
        int abase = (buf * 2 + mh) * 8192;
#pragma unroll
        for (int i = 0; i < 4; ++i) {
            int rl = wr * 64 + i * 16 + fr;
            int rsw = rl & 7;
#pragma unroll
            for (int ks = 0; ks < 2; ++ks)
                af[i][ks] = *(const short8v*)&lds[abase + rl * 64 + (((ks * 4 + kl) ^ rsw) * 8)];
        }
    };
    auto LOAD_B = [&](int buf, int nh, short8v (&bf)[2][2]) {
        int bbase = 32768 + (buf * 2 + nh) * 8192;
#pragma unroll
        for (int j = 0; j < 2; ++j) {
            int rl = wc * 32 + j * 16 + fr;
            int rsw = rl & 7;
#pragma unroll
            for (int ks = 0; ks < 2; ++ks)
                bf[j][ks] = *(const short8v*)&lds[bbase + rl * 64 + (((ks * 4 + kl) ^ rsw) * 8)];
        }
    };
    auto MFMA_Q = [&](int mh, int nh, short8v (&bf)[2][2]) {
        __builtin_amdgcn_s_setprio(1);
#pragma unroll
        for (int i = 0; i < 4; ++i)
#pragma unroll
            for (int j = 0; j < 2; ++j)
#pragma unroll
                for (int ks = 0; ks < 2; ++ks)
                    acc[mh * 4 + i][nh * 2 + j] = __builtin_amdgcn_mfma_f32_16x16x32_bf16(
                        af[i][ks], bf[j][ks], acc[mh * 4 + i][nh * 2 + j], 0, 0, 0);
        __builtin_amdgcn_s_setprio(0);
    };

#define GBAR  __builtin_amdgcn_s_barrier(); __builtin_amdgcn_sched_barrier(0);
#define LGKM  asm volatile("s_waitcnt lgkmcnt(0)" ::: "memory"); __builtin_amdgcn_sched_barrier(0);

    STAGE(1, 0, 0, 0); STAGE(0, 0, 0, 0);
    STAGE(1, 0, 1, 0); STAGE(0, 0, 1, 0);
    STAGE(1, 1, 0, 1); STAGE(0, 1, 0, 1);

    int T = K >> 7;
    for (int t = 0; t < T; ++t) {
        int last = (t == T - 1);
        asm volatile("s_waitcnt vmcnt(4)" ::: "memory");
        STAGE(1, 1, 1, 2 * t + 1);
        GBAR;
        LOAD_A(0, 0); LOAD_B(0, 0, bfA);
        LGKM; MFMA_Q(0, 0, bfA);
        GBAR;
        STAGE(0, 1, 1, 2 * t + 1);
        GBAR;
        LOAD_B(0, 1, bfB);
        LGKM; MFMA_Q(0, 1, bfB);
        GBAR;
        if (!last) STAGE(1, 0, 0, 2 * t + 2);
        GBAR;
        LOAD_A(0, 1);
        LGKM; MFMA_Q(1, 1, bfB);
        GBAR;
        if (!last) STAGE(0, 0, 0, 2 * t + 2);
        GBAR;
        MFMA_Q(1, 0, bfA);
        GBAR;
        if (last) { asm volatile("s_waitcnt vmcnt(0)" ::: "memory"); }
        else      { asm volatile("s_waitcnt vmcnt(4)" ::: "memory"); }
        if (!last) STAGE(1, 0, 1, 2 * t + 2);
        GBAR;
        LOAD_A(1, 0); LOAD_B(1, 0, bfA);
        LGKM; MFMA_Q(0, 0, bfA);
        GBAR;
        if (!last) STAGE(0, 0, 1, 2 * t + 2);
        GBAR;
        LOAD_B(1, 1, bfB);
        LGKM; MFMA_Q(0, 1, bfB);
        GBAR;
        if (!last) STAGE(1, 1, 0, 2 * t + 3);
        GBAR;
        LOAD_A(1, 1);
        LGKM; MFMA_Q(1, 1, bfB);
        GBAR;
        if (!last) STAGE(0, 1, 0, 2 * t + 3);
        GBAR;
        MFMA_Q(1, 0, bfA);
        GBAR;
    }
#undef GBAR
#undef LGKM

    int cr = (lane >> 4) * 4, cc = lane & 15;
#pragma unroll
    for (int i8 = 0; i8 < 8; ++i8) {
        int mh = i8 >> 2, ii = i8 & 3;
        int row0 = bm + mh * 128 + wr * 64 + ii * 16 + cr;
#pragma unroll
        for (int p = 0; p < 4; ++p) {
            short* Cp = C + (size_t)(row0 + p) * N + bn;
#pragma unroll
            for (int j4 = 0; j4 < 4; ++j4) {
                int nh = j4 >> 1, jj = j4 & 1;
                Cp[nh * 128 + wc * 32 + jj * 16 + cc] = f2bf(acc[i8][j4][p]);
            }
        }
    }
}

// -------- 128x128 bf16 GEMM: BK=64, XOR-swizzled LDS, dbuf counted-vmcnt,
// -------- optional split-K (nsk>1: f32 partials at Cv + sk*M*N).
__global__ __launch_bounds__(256) void gemm_bf16_kernel(
    const short* __restrict__ A, const short* __restrict__ W,
    void* __restrict__ Cv, int M, int N, int K,
    const float* __restrict__ bias, int epilogue, int nsk)
{
    __shared__ __align__(16) short As[2][128 * 64];
    __shared__ __align__(16) short Bs[2][128 * 64];
    int tid = threadIdx.x;
    int lane = tid & 63, wv = tid >> 6;
    int nbx = N >> 7;
    int nwg = (M >> 7) * nbx;
    int ntot = nwg * nsk;
    int q = ntot >> 3;
    int wgz = ((int)blockIdx.x & 7) * q + ((int)blockIdx.x >> 3);
    int sk = wgz / nwg;
    int wg = wgz % nwg;
    int bx = wg % nbx, by = wg / nbx;
    int bm = by * 128, bn = bx * 128;
    int wr = wv >> 1, wc = wv & 1;
    int Kl = K / nsk;
    int koff = sk * Kl;

    const int fr = lane & 15;
    const int kl = lane >> 4;
    const int srow = lane >> 3;
    const int schunk = (lane & 7) ^ (srow & 7);

    f32x4 acc[4][4] = {};

    const short* Ab = A + (size_t)bm * K + koff;
    const short* Bb = W + (size_t)bn * K + koff;

    auto STAGE = [&](int buf, int kt) {
        int ko = kt << 6;
#pragma unroll
        for (int s = 0; s < 4; ++s) {
            int row = s * 32 + wv * 8 + srow;
            async16(&As[buf][s * 2048 + wv * 512], Ab + (size_t)row * K + ko + schunk * 8);
            async16(&Bs[buf][s * 2048 + wv * 512], Bb + (size_t)row * K + ko + schunk * 8);
        }
    };

    int NT = Kl >> 6;
    STAGE(0, 0);
    if (NT > 1) STAGE(1, 1);

    for (int t = 0; t < NT; ++t) {
        if (t + 1 < NT) { asm volatile("s_waitcnt vmcnt(8)" ::: "memory"); }
        else            { asm volatile("s_waitcnt vmcnt(0)" ::: "memory"); }
        __builtin_amdgcn_s_barrier();
        __builtin_amdgcn_sched_barrier(0);
        int buf = t & 1;
        short8v af[4][2], bf[4][2];
#pragma unroll
        for (int i = 0; i < 4; ++i) {
            int rl = wr * 64 + i * 16 + fr;
            int rsw = rl & 7;
#pragma unroll
            for (int ks = 0; ks < 2; ++ks)
                af[i][ks] = *(const short8v*)&As[buf][rl * 64 + (((ks * 4 + kl) ^ rsw) * 8)];
        }
#pragma unroll
        for (int j = 0; j < 4; ++j) {
            int rl = wc * 64 + j * 16 + fr;
            int rsw = rl & 7;
#pragma unroll
            for (int ks = 0; ks < 2; ++ks)
                bf[j][ks] = *(const short8v*)&Bs[buf][rl * 64 + (((ks * 4 + kl) ^ rsw) * 8)];
        }
        asm volatile("s_waitcnt lgkmcnt(0)" ::: "memory");
        __builtin_amdgcn_sched_barrier(0);
        __builtin_amdgcn_s_setprio(1);
#pragma unroll
        for (int i = 0; i < 4; ++i)
#pragma unroll
            for (int j = 0; j < 4; ++j)
#pragma unroll
                for (int ks = 0; ks < 2; ++ks)
                    acc[i][j] = __builtin_amdgcn_mfma_f32_16x16x32_bf16(
                        af[i][ks], bf[j][ks], acc[i][j], 0, 0, 0);
        __builtin_amdgcn_s_setprio(0);
        __builtin_amdgcn_s_barrier();
        __builtin_amdgcn_sched_barrier(0);
        if (t + 2 < NT) STAGE(buf, t + 2);
    }

    int cr = (lane >> 4) * 4, cc = lane & 15;
    size_t skoff = (size_t)sk * M * N;
#pragma unroll
    for (int i = 0; i < 4; ++i)
#pragma unroll
        for (int p = 0; p < 4; ++p) {
            int row = bm + wr * 64 + i * 16 + cr + p;
#pragma unroll
            for (int j = 0; j < 4; ++j) {
                int col = bn + wc * 64 + cc + j * 16;
                float v = acc[i][j][p];
                if (epilogue == 2)
                    ((short*)Cv)[(size_t)row * N + col] = f2bf(v);
                else
                    ((float*)Cv)[skoff + (size_t)row * N + col] = v;
            }
        }
}

// ---------------- sum OSK split-K partials -> f32 dst (final layer)
__global__ __launch_bounds__(256) void osum_kernel(
    const float* __restrict__ P, float* __restrict__ out)
{
    size_t i = ((size_t)blockIdx.x * 256 + threadIdx.x) * 4;
    float4 a = *(const float4*)(P + i);
    float4 b = *(const float4*)(P + (size_t)BQ * LQ * D_MODEL + i);
    a.x += b.x; a.y += b.y; a.z += b.z; a.w += b.w;
    *(float4*)(out + i) = a;
}

// ---------- dt_proj: K=64 direct-register MFMA, no LDS, no barriers.
__global__ __launch_bounds__(256) void dtproj_kernel(
    const short* __restrict__ A, const short* __restrict__ W,
    const float* __restrict__ bias, short* __restrict__ Out)
{
    int lane = threadIdx.x & 63, w = threadIdx.x >> 6;
    int m0 = blockIdx.y * 64 + w * 16;
    int bn = blockIdx.x * 128;
    int fr = lane & 15, fk = (lane >> 4) * 8;
    const short* Ap = A + (size_t)(m0 + fr) * DT_RANK + fk;
    short8v a0 = *(const short8v*)(Ap);
    short8v a1 = *(const short8v*)(Ap + 32);
    f32x4 acc[8] = {};
#pragma unroll
    for (int j = 0; j < 8; ++j) {
        const short* Wp = W + (size_t)(bn + j * 16 + fr) * DT_RANK + fk;
        short8v b0 = *(const short8v*)(Wp);
        short8v b1 = *(const short8v*)(Wp + 32);
        acc[j] = __builtin_amdgcn_mfma_f32_16x16x32_bf16(a0, b0, acc[j], 0, 0, 0);
        acc[j] = __builtin_amdgcn_mfma_f32_16x16x32_bf16(a1, b1, acc[j], 0, 0, 0);
    }
    int cr = (lane >> 4) * 4, cc = lane & 15;
#pragma unroll
    for (int j = 0; j < 8; ++j) {
        int col = bn + j * 16 + cc;
        float bv = bias[col];
#pragma unroll
        for (int p = 0; p < 4; ++p) {
            float v = acc[j][p] + bv;
            v = (v > 20.f) ? v : __logf(1.f + __expf(v));
            Out[(size_t)(m0 + cr + p) * D_INNER + col] = f2bf(v);
        }
    }
}

// ------------------------- x_proj: tall-skinny split-K bf16 MFMA, no LDS
__global__ __launch_bounds__(256) void xproj_kernel(
    const short* __restrict__ A, const short* __restrict__ W,
    float* __restrict__ Xpart)
{
    int lane = threadIdx.x & 63, wv = threadIdx.x >> 6;
    int sk = blockIdx.x;
    int m0 = blockIdx.y * 64 + wv * 16;
    int fr = lane & 15, fk = (lane >> 4) * 8;
    const short* Ap = A + (size_t)(m0 + fr) * D_INNER + sk * XKC + fk;
    const short* Wp = W + (size_t)fr * D_INNER + sk * XKC + fk;
    f32x4 acc[6] = {};
    for (int k = 0; k < XKC; k += 32) {
        short8v af = *(const short8v*)(Ap + k);
#pragma unroll
        for (int j = 0; j < 6; ++j) {
            short8v bf = *(const short8v*)(Wp + (size_t)j * 16 * D_INNER + k);
            acc[j] = __builtin_amdgcn_mfma_f32_16x16x32_bf16(af, bf, acc[j], 0, 0, 0);
        }
    }
    int cr = (lane >> 4) * 4, cc = lane & 15;
    float* Op = Xpart + ((size_t)sk * (BQ * LQ) + m0 + cr) * 96 + cc;
#pragma unroll
    for (int j = 0; j < 6; ++j)
#pragma unroll
        for (int p = 0; p < 4; ++p)
            Op[(size_t)p * 96 + j * 16] = acc[j][p];
}

// reduce split-K partials -> xdbl f32; also emit compact bf16 dt_r [BL][64]
__global__ __launch_bounds__(256) void xreduce_kernel(
    const float* __restrict__ Xpart, float* __restrict__ xdbl,
    short* __restrict__ dtr)
{
    size_t i = (size_t)blockIdx.x * 256 + threadIdx.x;
    float s = 0.f;
#pragma unroll
    for (int sk = 0; sk < XSPLITK; ++sk)
        s += Xpart[(size_t)sk * ((size_t)BQ * LQ * 96) + i];
    xdbl[i] = s;
    int col = (int)(i % 96);
    if (col < DT_RANK)
        dtr[(i / 96) * DT_RANK + col] = f2bf(s);
}

// --------------------------- causal conv + SiLU, 4 channels/thread
__global__ __launch_bounds__(256) void conv_silu_kernel(
    const unsigned short* __restrict__ uz, short* __restrict__ outb,
    const float* __restrict__ w, const float* __restrict__ bias)
{
    int idx = blockIdx.x * 256 + threadIdx.x;        // over BLDI/4
    int e0 = idx * 4;
    int c = e0 & (D_INNER - 1);
    int bl = e0 / D_INNER;
    int l = bl & (LQ - 1);
    int b = bl / LQ;
    float acc[4] = {bias[c], bias[c + 1], bias[c + 2], bias[c + 3]};
    float wv[4][D_CONV];
#pragma unroll
    for (int j = 0; j < 4; ++j)
#pragma unroll
        for (int k = 0; k < D_CONV; ++k)
            wv[j][k] = w[(c + j) * D_CONV + k];
#pragma unroll
    for (int k = 0; k < D_CONV; ++k) {
        int ls = l - (D_CONV - 1) + k;
        if (ls >= 0) {
            ushort4 v = *(const ushort4*)&uz[((size_t)b * LQ + ls) * (2 * D_INNER) + c];
            acc[0] += bf2f(v.x) * wv[0][k];
            acc[1] += bf2f(v.y) * wv[1][k];
            acc[2] += bf2f(v.z) * wv[2][k];
            acc[3] += bf2f(v.w) * wv[3][k];
        }
    }
    short4 o;
    o.x = f2bf(acc[0] / (1.f + __expf(-acc[0])));
    o.y = f2bf(acc[1] / (1.f + __expf(-acc[1])));
    o.z = f2bf(acc[2] / (1.f + __expf(-acc[2])));
    o.w = f2bf(acc[3] / (1.f + __expf(-acc[3])));
    *(short4*)&outb[e0] = o;
}

// -------------------------------------------- selective scan, chunked 3-phase
// phase 1: async-LDS-staged u/dt (T14), dA-powers fast path; f32 Fbuf.
__global__ __launch_bounds__(256) void scan_phase1_kernel(
    const unsigned short* __restrict__ u, const unsigned short* __restrict__ dt,
    const float* __restrict__ xdbl, const float* __restrict__ A_log,
    float* __restrict__ dtsumb, float* __restrict__ Fbuf)
{
    __shared__ float S[CHUNK][D_STATE];
    __shared__ __align__(16) unsigned short Ub[2][8][256];
    __shared__ __align__(16) unsigned short Db[2][8][256];
    int t = threadIdx.x;
    int d0 = blockIdx.x * 256;
    int d = d0 + t;
    int c = blockIdx.y;
    int b = blockIdx.z;
    int l0 = c * CHUNK;
    {
        int row = t >> 3, cc2 = (t & 7) * 2;
        const float* src = xdbl + ((size_t)(b * LQ + l0 + row)) * 96 + DT_RANK + cc2;
        *(float2*)&S[row][cc2] = *(const float2*)src;
    }
    const int w = t >> 6, lane = t & 63;
    const int srw = 2 * w + (lane >> 5);
    const int scl = (lane & 31) * 8;
    const unsigned short* ubp = u  + ((size_t)b * LQ + l0) * D_INNER + d0;
    const unsigned short* dbp = dt + ((size_t)b * LQ + l0) * D_INNER + d0;
    auto STAGE1 = [&](int buf, int lb) {
        async16(&Ub[buf][2 * w][0], ubp + (size_t)(lb + srw) * D_INNER + scl);
        async16(&Db[buf][2 * w][0], dbp + (size_t)(lb + srw) * D_INNER + scl);
    };
    STAGE1(0, 0);

    float A[D_STATE], h[D_STATE];
    {
        const float4* ap = (const float4*)(A_log + (size_t)d * D_STATE);
#pragma unroll
        for (int g = 0; g < 4; ++g) {
            float4 a = ap[g];
            A[g*4+0] = -__expf(a.x); A[g*4+1] = -__expf(a.y);
            A[g*4+2] = -__expf(a.z); A[g*4+3] = -__expf(a.w);
        }
    }
    bool pf = true;
#pragma unroll
    for (int n = 1; n < D_STATE; ++n)
        pf = pf && (fabsf(A[n] - (float)(n + 1) * A[0]) <= 1e-4f * (float)(n + 1));
#pragma unroll
    for (int n = 0; n < D_STATE; ++n) h[n] = 0.f;
    float dtsum = 0.f;
    float A0 = A[0];
    asm volatile("s_waitcnt lgkmcnt(0)" ::: "memory");

    for (int bb = 0; bb < CHUNK / 8; ++bb) {
        int buf = bb & 1;
        if (bb + 1 < CHUNK / 8) {
            STAGE1(buf ^ 1, (bb + 1) * 8);
            asm volatile("s_waitcnt vmcnt(2)" ::: "memory");
        } else {
            asm volatile("s_waitcnt vmcnt(0)" ::: "memory");
        }
        __builtin_amdgcn_s_barrier();
        __builtin_amdgcn_sched_barrier(0);
        float uvv[8], dtvv[8];
#pragma unroll
        for (int i = 0; i < 8; ++i) {
            uvv[i]  = bf2f(Ub[buf][i][t]);
            dtvv[i] = bf2f(Db[buf][i][t]);
        }
        if (pf) {
#pragma unroll
            for (int i = 0; i < 8; ++i) {
                int l = bb * 8 + i;
                float dtv = dtvv[i];
                float du = dtv * uvv[i];
                dtsum += dtv;
                float dA[D_STATE];
                dA_powers(__expf(dtv * A0), dA);
#pragma unroll
                for (int n4 = 0; n4 < D_STATE; n4 += 4) {
                    float4 Bv = *(const float4*)&S[l][n4];
                    float bb2[4] = {Bv.x, Bv.y, Bv.z, Bv.w};
#pragma unroll
                    for (int k = 0; k < 4; ++k) {
                        int n = n4 + k;
                        h[n] = dA[n] * h[n] + du * bb2[k];
                    }
                }
            }
        } else {
#pragma unroll
            for (int i = 0; i < 8; ++i) {
                int l = bb * 8 + i;
                float dtv = dtvv[i];
                float du = dtv * uvv[i];
                dtsum += dtv;
#pragma unroll
                for (int n4 = 0; n4 < D_STATE; n4 += 4) {
                    float4 Bv = *(const float4*)&S[l][n4];
                    float bb2[4] = {Bv.x, Bv.y, Bv.z, Bv.w};
#pragma unroll
                    for (int k = 0; k < 4; ++k) {
                        int n = n4 + k;
                        float dA = __expf(dtv * A[n]);
                        h[n] = dA * h[n] + du * bb2[k];
                    }
                }
            }
        }
        __builtin_amdgcn_s_barrier();
        __builtin_amdgcn_sched_barrier(0);
    }
    dtsumb[(size_t)(b * NCHUNK + c) * D_INNER + d] = dtsum;
    size_t base = ((size_t)(b * NCHUNK + c) * D_STATE) * D_INNER + d;
#pragma unroll
    for (int n = 0; n < D_STATE; ++n)
        Fbuf[base + (size_t)n * D_INNER] = h[n];
}

// phase 2: sequential combine; P = exp(A * dtsum) recomputed here
__global__ __launch_bounds__(256) void scan_phase2_kernel(
    const float* __restrict__ dtsumb, const float* __restrict__ A_log,
    float* __restrict__ Fbuf)
{
    int d = blockIdx.x * 256 + threadIdx.x;
    int n = blockIdx.y;
    int b = blockIdx.z;
    float A = -__expf(A_log[(size_t)d * D_STATE + n]);
    float hinit = 0.f;
    for (int c = 0; c < NCHUNK; ++c) {
        size_t idx = ((size_t)(b * NCHUNK + c) * D_STATE + n) * D_INNER + d;
        float F = Fbuf[idx];
        float P = __expf(A * dtsumb[(size_t)(b * NCHUNK + c) * D_INNER + d]);
        Fbuf[idx] = hinit;
        hinit = P * hinit + F;
    }
}

// phase 3: async-LDS-staged u/dt/z (T14), B+C XOR-swizzled, dA-powers,
// fused gate, bf16 out; f32 Hinit.
__global__ __launch_bounds__(256) void scan_phase3_kernel(
    const unsigned short* __restrict__ u, const unsigned short* __restrict__ dt,
    const float* __restrict__ xdbl, const float* __restrict__ A_log,
    const float* __restrict__ Dp, const float* __restrict__ Hinit,
    const unsigned short* __restrict__ uz, short* __restrict__ yout)
{
    __shared__ float S[CHUNK][32];
    __shared__ __align__(16) unsigned short Ub[2][8][256];
    __shared__ __align__(16) unsigned short Db[2][8][256];
    __shared__ __align__(16) unsigned short Zb[2][8][256];
    int t = threadIdx.x;
    int d0 = blockIdx.x * 256;
    int d = d0 + t;
    int c = blockIdx.y;
    int b = blockIdx.z;
    int l0 = c * CHUNK;
    {
        int row = t >> 3, cg = (t & 7) * 4;
        const float* src = xdbl + ((size_t)(b * LQ + l0 + row)) * 96 + DT_RANK + cg;
        *(float4*)&S[row][cg ^ ((row & 7) << 2)] = *(const float4*)src;
    }
    const int w = t >> 6, lane = t & 63;
    const int srw = 2 * w + (lane >> 5);
    const int scl = (lane & 31) * 8;
    const unsigned short* ubp = u  + ((size_t)b * LQ + l0) * D_INNER + d0;
    const unsigned short* dbp = dt + ((size_t)b * LQ + l0) * D_INNER + d0;
    const unsigned short* zbp = uz + ((size_t)b * LQ + l0) * (2 * D_INNER) + D_INNER + d0;
    auto STAGE3 = [&](int buf, int lb) {
        async16(&Ub[buf][2 * w][0], ubp + (size_t)(lb + srw) * D_INNER + scl);
        async16(&Db[buf][2 * w][0], dbp + (size_t)(lb + srw) * D_INNER + scl);
        async16(&Zb[buf][2 * w][0], zbp + (size_t)(lb + srw) * (2 * D_INNER) + scl);
    };
    STAGE3(0, 0);

    float A[D_STATE], h[D_STATE];
    {
        const float4* ap = (const float4*)(A_log + (size_t)d * D_STATE);
#pragma unroll
        for (int g = 0; g < 4; ++g) {
            float4 a = ap[g];
            A[g*4+0] = -__expf(a.x); A[g*4+1] = -__expf(a.y);
            A[g*4+2] = -__expf(a.z); A[g*4+3] = -__expf(a.w);
        }
    }
    bool pf = true;
#pragma unroll
    for (int n = 1; n < D_STATE; ++n)
        pf = pf && (fabsf(A[n] - (float)(n + 1) * A[0]) <= 1e-4f * (float)(n + 1));
    size_t base = ((size_t)(b * NCHUNK + c) * D_STATE) * D_INNER + d;
#pragma unroll
    for (int n = 0; n < D_STATE; ++n)
        h[n] = Hinit[base + (size_t)n * D_INNER];
    float Dd = Dp[d];
    float A0 = A[0];
    short* yp = yout + ((size_t)b * LQ + l0) * D_INNER + d;
    asm volatile("s_waitcnt lgkmcnt(0)" ::: "memory");

    for (int bb = 0; bb < CHUNK / 8; ++bb) {
        int buf = bb & 1;
        if (bb + 1 < CHUNK / 8) {
            STAGE3(buf ^ 1, (bb + 1) * 8);
            asm volatile("s_waitcnt vmcnt(3)" ::: "memory");
        } else {
            asm volatile("s_waitcnt vmcnt(0)" ::: "memory");
        }
        __builtin_amdgcn_s_barrier();
        __builtin_amdgcn_sched_barrier(0);
        float uvv[8], dtvv[8], zvv[8];
#pragma unroll
        for (int i = 0; i < 8; ++i) {
            uvv[i]  = bf2f(Ub[buf][i][t]);
            dtvv[i] = bf2f(Db[buf][i][t]);
            zvv[i]  = bf2f(Zb[buf][i][t]);
        }
        if (pf) {
#pragma unroll
            for (int i = 0; i < 8; ++i) {
                int l = bb * 8 + i;
                float dtv = dtvv[i];
                float du = dtv * uvv[i];
                float acc = 0.f;
                int sw = (l & 7) << 2;
                float dA[D_STATE];
                dA_powers(__expf(dtv * A0), dA);
#pragma unroll
                for (int n4 = 0; n4 < D_STATE; n4 += 4) {
                    float4 Bv = *(const float4*)&S[l][n4 ^ sw];
                    float4 Cv = *(const float4*)&S[l][(16 + n4) ^ sw];
                    float bb2[4] = {Bv.x, Bv.y, Bv.z, Bv.w};
                    float cc2[4] = {Cv.x, Cv.y, Cv.z, Cv.w};
#pragma unroll
                    for (int k = 0; k < 4; ++k) {
                        int n = n4 + k;
                        h[n] = dA[n] * h[n] + du * bb2[k];
                        acc += h[n] * cc2[k];
                    }
                }
                float y = acc + uvv[i] * Dd;
                float zv = zvv[i];
                float g = zv / (1.f + __expf(-zv));
                yp[(size_t)l * D_INNER] = f2bf(y * g);
            }
        } else {
#pragma unroll
            for (int i = 0; i < 8; ++i) {
                int l = bb * 8 + i;
                float dtv = dtvv[i];
                float du = dtv * uvv[i];
                float acc = 0.f;
                int sw = (l & 7) << 2;
#pragma unroll
                for (int n4 = 0; n4 < D_STATE; n4 += 4) {
                    float4 Bv = *(const float4*)&S[l][n4 ^ sw];
                    float4 Cv = *(const float4*)&S[l][(16 + n4) ^ sw];
                    float bb2[4] = {Bv.x, Bv.y, Bv.z, Bv.w};
                    float cc2[4] = {Cv.x, Cv.y, Cv.z, Cv.w};
#pragma unroll
                    for (int k = 0; k < 4; ++k) {
                        int n = n4 + k;
                        float dA = __expf(dtv * A[n]);
                        h[n] = dA * h[n] + du * bb2[k];
                        acc += h[n] * cc2[k];
                    }
                }
                float y = acc + uvv[i] * Dd;
                float zv = zvv[i];
                float g = zv / (1.f + __expf(-zv));
                yp[(size_t)l * D_INNER] = f2bf(y * g);
            }
        }
        __builtin_amdgcn_s_barrier();
        __builtin_amdgcn_sched_barrier(0);
    }
}

// --------------- all 4 weight tensors -> bf16 in ONE launch
__global__ __launch_bounds__(256) void convert_all_kernel(
    const float* __restrict__ w_in, const float* __restrict__ w_out,
    const float* __restrict__ w_xp, const float* __restrict__ w_dt,
    short* __restrict__ wbuf)
{
    const int IN_B  = (2 * D_INNER * D_MODEL) / 1024;
    const int OUT_B = (D_MODEL * D_INNER) / 1024;
    const int XP_B  = (96 * D_INNER) / 1024;
    int blk = blockIdx.x;
    const float* src; short* dst;
    if (blk < IN_B)                 { src = w_in;  dst = wbuf; }
    else if (blk < IN_B + OUT_B)    { src = w_out; dst = wbuf + 2 * D_INNER * D_MODEL; blk -= IN_B; }
    else if (blk < IN_B + OUT_B + XP_B) { src = w_xp; dst = wbuf + 2 * D_INNER * D_MODEL + D_MODEL * D_INNER; blk -= IN_B + OUT_B; }
    else { src = w_dt; dst = wbuf + 2 * D_INNER * D_MODEL + D_MODEL * D_INNER + 96 * D_INNER; blk -= IN_B + OUT_B + XP_B; }
    int i = blk * 1024 + threadIdx.x * 4;
    float4 v = *(const float4*)(src + i);
    short4 o = make_short4(f2bf(v.x), f2bf(v.y), f2bf(v.z), f2bf(v.w));
    *(short4*)(dst + i) = o;
}

// ---------------------------------------------------------------- launcher
extern "C" void kernel_launch(void* const* d_in, const int* in_sizes, int n_in,
                              void* d_out, int out_size, void* d_ws, size_t ws_size,
                              hipStream_t stream)
{
    const float* x        = (const float*)d_in[0];
    const float* norm_w   = (const float*)d_in[2];
    const float* norm_b   = (const float*)d_in[3];
    const float* in_proj  = (const float*)d_in[4];
    const float* conv_w   = (const float*)d_in[5];
    const float* conv_b   = (const float*)d_in[6];
    const float* x_proj   = (const float*)d_in[7];
    const float* dt_proj  = (const float*)d_in[8];
    const float* dt_projb = (const float*)d_in[9];
    const float* A_log    = (const float*)d_in[10];
    const float* Dp       = (const float*)d_in[11];
    const float* out_proj = (const float*)d_in[12];
    float* out = (float*)d_out;
    float* ws  = (float*)d_ws;

    const size_t BL   = (size_t)BQ * LQ;            // 4096
    const size_t BLDM = BL * D_MODEL;
    const size_t BLDI = BL * D_INNER;
    const int IN_W  = 2 * D_INNER * D_MODEL;
    const int OUT_W = D_MODEL * D_INNER;
    const int XP_W  = 96 * D_INNER;
    const int DT_W  = D_INNER * DT_RANK;
    const int CV_BLOCKS = (IN_W + OUT_W + XP_W + DT_W) / 1024;

    size_t o = 0;
    short* hnb   = (short*)(ws + o); o += BLDM / 2;
    short* uzb   = (short*)(ws + o); o += BL * 2 * D_INNER / 2;
    short* dtb   = (short*)(ws + o); o += BLDI / 2;
    float* xdbl  = ws + o; o += BL * 96;
    float* Xpart = ws + o; o += (size_t)XSPLITK * BL * 96;
    float* Fbuf  = ws + o; o += (size_t)BQ * NCHUNK * D_STATE * D_INNER;
    float* dtsumb = ws + o; o += (size_t)BQ * NCHUNK * D_INNER;
    short* ucx   = (short*)(ws + o); o += BLDI / 2;
    short* dtr   = (short*)(ws + o); o += BL * DT_RANK / 2;
    float* Opart = ws + o; o += (size_t)OSK * BLDM;
    short* wbuf  = (short*)(ws + o);
    o += (size_t)(IN_W + OUT_W + XP_W + DT_W + 1) / 2;

    for (int layer = 0; layer < DEPTH; ++layer) {
        if (layer == 0)
            layernorm_kernel<<<(int)BL, 256, 0, stream>>>(
                x, norm_w, norm_b, hnb);

        convert_all_kernel<<<CV_BLOCKS, 256, 0, stream>>>(
            in_proj + (size_t)layer * IN_W, out_proj + (size_t)layer * OUT_W,
            x_proj + (size_t)layer * XP_W, dt_proj + (size_t)layer * DT_W, wbuf);

        gemm256_bf16_kernel<<<(int)(BL / 256) * (2 * D_INNER / 256), 512, 0, stream>>>(
            hnb, wbuf, uzb, (int)BL, 2 * D_INNER, D_MODEL);

        conv_silu_kernel<<<(int)(BLDI / 1024), 256, 0, stream>>>(
            (const unsigned short*)uzb, ucx,
            conv_w + (size_t)layer * D_INNER * D_CONV,
            conv_b + (size_t)layer * D_INNER);

        xproj_kernel<<<dim3(XSPLITK, BL / 64), 256, 0, stream>>>(
            ucx, wbuf + IN_W + OUT_W, Xpart);
        xreduce_kernel<<<(int)(BL * 96 / 256), 256, 0, stream>>>(Xpart, xdbl, dtr);

        dtproj_kernel<<<dim3(D_INNER / 128, BL / 64), 256, 0, stream>>>(
            dtr, wbuf + IN_W + OUT_W + XP_W,
            dt_projb + (size_t)layer * D_INNER, dtb);

        const float* Al = A_log + (size_t)layer * D_INNER * D_STATE;
        scan_phase1_kernel<<<dim3(D_INNER / 256, NCHUNK, BQ), 256, 0, stream>>>(
            (const unsigned short*)ucx, (const unsigned short*)dtb, xdbl, Al,
            dtsumb, Fbuf);
        scan_phase2_kernel<<<dim3(D_INNER / 256, D_STATE, BQ), 256, 0, stream>>>(
            dtsumb, Al, Fbuf);
        scan_phase3_kernel<<<dim3(D_INNER / 256, NCHUNK, BQ), 256, 0, stream>>>(
            (const unsigned short*)ucx, (const unsigned short*)dtb, xdbl, Al,
            Dp + (size_t)layer * D_INNER, Fbuf,
            (const unsigned short*)uzb, (short*)ucx);

        gemm_bf16_kernel<<<(int)(BL / 128) * (D_MODEL / 128) * OSK, 256, 0, stream>>>(
            ucx, wbuf + IN_W, Opart, (int)BL, D_MODEL, D_INNER, nullptr, 0, OSK);

        if (layer == DEPTH - 1)
            osum_kernel<<<(int)(BLDM / 1024), 256, 0, stream>>>(Opart, out);
        else
            osum_ln_kernel<<<(int)BL, 256, 0, stream>>>(
                Opart, norm_w + (size_t)(layer + 1) * D_MODEL,
                norm_b + (size_t)(layer + 1) * D_MODEL, hnb);
    }
}

// Round 24
// 402.515 us; speedup vs baseline: 1.0227x; 1.0116x over previous
//
#include <hip/hip_runtime.h>
#include <hip/hip_bf16.h>
#include <math.h>

#define BQ 2
#define LQ 2048
#define D_MODEL 1024
#define D_INNER 2048
#define D_STATE 16
#define DT_RANK 64
#define D_CONV 4
#define DEPTH 2
#define NCHUNK 64
#define CHUNK 32
#define XSPLITK 8
#define XKC (D_INNER / XSPLITK)   // 256
#define OSK 2                     // out_proj split-K

typedef __attribute__((ext_vector_type(8))) short short8v;  // 8 bf16 (4 VGPRs)
typedef __attribute__((ext_vector_type(4))) float f32x4;

__device__ __forceinline__ short f2bf(float f) {
    union { float f; unsigned u; } v; v.f = f;
    unsigned r = v.u + 0x7fffu + ((v.u >> 16) & 1u);   // RNE
    return (short)(r >> 16);
}

__device__ __forceinline__ float bf2f(unsigned short s) {
    union { unsigned u; float f; } v; v.u = ((unsigned)s) << 16;
    return v.f;
}

__device__ __forceinline__ void async16(void* lds, const void* gp) {
    __builtin_amdgcn_global_load_lds(
        (const __attribute__((address_space(1))) void*)gp,
        (__attribute__((address_space(3))) void*)lds, 16, 0, 0);
}

// dA[n] = e1^(n+1) via 3 squarings + 12 muls (valid when A[n]=(n+1)A[0])
__device__ __forceinline__ void dA_powers(float e1, float* dA) {
    float e2 = e1 * e1, e4 = e2 * e2, e8 = e4 * e4;
    dA[0] = e1;       dA[1] = e2;       dA[2] = e2 * e1;  dA[3] = e4;
    dA[4] = e4 * e1;  dA[5] = e4 * e2;  dA[6] = e4 * dA[2]; dA[7] = e8;
    dA[8] = e8 * e1;  dA[9] = e8 * e2;  dA[10] = e8 * dA[2]; dA[11] = e8 * e4;
    dA[12] = e8 * dA[4]; dA[13] = e8 * dA[5]; dA[14] = e8 * dA[6]; dA[15] = e8 * e8;
}

// ------------------------------------------------- LayerNorm (bf16 output)
__global__ __launch_bounds__(256) void layernorm_kernel(
    const float* __restrict__ x, const float* __restrict__ w,
    const float* __restrict__ b, short* __restrict__ out)
{
    __shared__ float red[8];
    int row = blockIdx.x;
    const float* xr = x + (size_t)row * D_MODEL;
    float v[4];
    float s = 0.f, sq = 0.f;
#pragma unroll
    for (int i = 0; i < 4; ++i) {
        v[i] = xr[threadIdx.x + i * 256];
        s += v[i];
        sq += v[i] * v[i];
    }
#pragma unroll
    for (int off = 32; off; off >>= 1) {
        s += __shfl_down(s, off, 64);
        sq += __shfl_down(sq, off, 64);
    }
    int wid = threadIdx.x >> 6, lane = threadIdx.x & 63;
    if (!lane) { red[wid] = s; red[4 + wid] = sq; }
    __syncthreads();
    s = red[0] + red[1] + red[2] + red[3];
    sq = red[4] + red[5] + red[6] + red[7];
    float mu = s * (1.f / D_MODEL);
    float var = sq * (1.f / D_MODEL) - mu * mu;
    float rstd = rsqrtf(var + 1e-5f);
#pragma unroll
    for (int i = 0; i < 4; ++i) {
        int c = threadIdx.x + i * 256;
        out[(size_t)row * D_MODEL + c] = f2bf((v[i] - mu) * rstd * w[c] + b[c]);
    }
}

// --------- sum OSK out_proj partials + LayerNorm (next layer input, bf16)
__global__ __launch_bounds__(256) void osum_ln_kernel(
    const float* __restrict__ P, const float* __restrict__ w,
    const float* __restrict__ b, short* __restrict__ out)
{
    __shared__ float red[8];
    int row = blockIdx.x;
    const float* p0 = P + (size_t)row * D_MODEL;
    const float* p1 = P + (size_t)BQ * LQ * D_MODEL + (size_t)row * D_MODEL;
    float v[4];
    float s = 0.f, sq = 0.f;
#pragma unroll
    for (int i = 0; i < 4; ++i) {
        int c = threadIdx.x + i * 256;
        v[i] = p0[c] + p1[c];
        s += v[i];
        sq += v[i] * v[i];
    }
#pragma unroll
    for (int off = 32; off; off >>= 1) {
        s += __shfl_down(s, off, 64);
        sq += __shfl_down(sq, off, 64);
    }
    int wid = threadIdx.x >> 6, lane = threadIdx.x & 63;
    if (!lane) { red[wid] = s; red[4 + wid] = sq; }
    __syncthreads();
    s = red[0] + red[1] + red[2] + red[3];
    sq = red[4] + red[5] + red[6] + red[7];
    float mu = s * (1.f / D_MODEL);
    float var = sq * (1.f / D_MODEL) - mu * mu;
    float rstd = rsqrtf(var + 1e-5f);
#pragma unroll
    for (int i = 0; i < 4; ++i) {
        int c = threadIdx.x + i * 256;
        out[(size_t)row * D_MODEL + c] = f2bf((v[i] - mu) * rstd * w[c] + b[c]);
    }
}

// =================== 256x256 8-phase bf16 GEMM (T1+T2+T3+T4+T5) ===========
__global__ __launch_bounds__(512) void gemm256_bf16_kernel(
    const short* __restrict__ A, const short* __restrict__ W,
    short* __restrict__ C, int M, int N, int K)
{
    __shared__ __align__(16) short lds[65536];   // 128 KB
    const int tid = threadIdx.x;
    const int lane = tid & 63;
    const int w = tid >> 6;              // 0..7
    const int wr = w >> 2, wc = w & 3;   // 2 x 4 wave grid

    int nbx = N >> 8;
    int nwg = (M >> 8) * nbx;
    int q = nwg >> 3;                    // nwg % 8 == 0
    int wg = ((int)blockIdx.x & 7) * q + ((int)blockIdx.x >> 3);
    int bx = wg % nbx, by = wg / nbx;
    int bm = by << 8, bn = bx << 8;

    const int fr = lane & 15;
    const int kl = lane >> 4;
    const int srow = lane >> 3;
    const int schunk = (lane & 7) ^ (srow & 7);

    f32x4 acc[8][4] = {};
    short8v af[4][2], bfA[2][2], bfB[2][2];

    auto STAGE = [&](int isA, int buf, int half, int kt) {
        const short* gp = isA ? A : W;
        int tile0 = isA ? bm : bn;
        int base = (isA ? 0 : 32768) + (buf * 2 + half) * 8192;
        int ko = kt << 6;
#pragma unroll
        for (int s = 0; s < 2; ++s) {
            int row = half * 128 + s * 64 + w * 8 + srow;
            const short* src = gp + (size_t)(tile0 + row) * K + ko + schunk * 8;
            async16(&lds[base + s * 4096 + w * 512], src);
        }
    };

    auto LOAD_A = [&](int buf, int mh) {
        int abase = (buf * 2 + mh) * 8192;
#pragma unroll
        for (int i = 0; i < 4; ++i) {
            int rl = wr * 64 + i * 16 + fr;
            int rsw = rl & 7;
#pragma unroll
            for (int ks = 0; ks < 2; ++ks)
                af[i][ks] = *(const short8v*)&lds[abase + rl * 64 + (((ks * 4 + kl) ^ rsw) * 8)];
        }
    };
    auto LOAD_B = [&](int buf, int nh, short8v (&bf)[2][2]) {
        int bbase = 32768 + (buf * 2 + nh) * 8192;
#pragma unroll
        for (int j = 0; j < 2; ++j) {
            int rl = wc * 32 + j * 16 + fr;
            int rsw = rl & 7;
#pragma unroll
            for (int ks = 0; ks < 2; ++ks)
                bf[j][ks] = *(const short8v*)&lds[bbase + rl * 64 + (((ks * 4 + kl) ^ rsw) * 8)];
        }
    };
    auto MFMA_Q = [&](int mh, int nh, short8v (&bf)[2][2]) {
        __builtin_amdgcn_s_setprio(1);
#pragma unroll
        for (int i = 0; i < 4; ++i)
#pragma unroll
            for (int j = 0; j < 2; ++j)
#pragma unroll
                for (int ks = 0; ks < 2; ++ks)
                    acc[mh * 4 + i][nh * 2 + j] = __builtin_amdgcn_mfma_f32_16x16x32_bf16(
                        af[i][ks], bf[j][ks], acc[mh * 4 + i][nh * 2 + j], 0, 0, 0);
        __builtin_amdgcn_s_setprio(0);
    };

#define GBAR  __builtin_amdgcn_s_barrier(); __builtin_amdgcn_sched_barrier(0);
#define LGKM  asm volatile("s_waitcnt lgkmcnt(0)" ::: "memory"); __builtin_amdgcn_sched_barrier(0);

    STAGE(1, 0, 0, 0); STAGE(0, 0, 0, 0);
    STAGE(1, 0, 1, 0); STAGE(0, 0, 1, 0);
    STAGE(1, 1, 0, 1); STAGE(0, 1, 0, 1);

    int T = K >> 7;
    for (int t = 0; t < T; ++t) {
        int last = (t == T - 1);
        asm volatile("s_waitcnt vmcnt(4)" ::: "memory");
        STAGE(1, 1, 1, 2 * t + 1);
        GBAR;
        LOAD_A(0, 0); LOAD_B(0, 0, bfA);
        LGKM; MFMA_Q(0, 0, bfA);
        GBAR;
        STAGE(0, 1, 1, 2 * t + 1);
        GBAR;
        LOAD_B(0, 1, bfB);
        LGKM; MFMA_Q(0, 1, bfB);
        GBAR;
        if (!last) STAGE(1, 0, 0, 2 * t + 2);
        GBAR;
        LOAD_A(0, 1);
        LGKM; MFMA_Q(1, 1, bfB);
        GBAR;
        if (!last) STAGE(0, 0, 0, 2 * t + 2);
        GBAR;
        MFMA_Q(1, 0, bfA);
        GBAR;
        if (last) { asm volatile("s_waitcnt vmcnt(0)" ::: "memory"); }
        else      { asm volatile("s_waitcnt vmcnt(4)" ::: "memory"); }
        if (!last) STAGE(1, 0, 1, 2 * t + 2);
        GBAR;
        LOAD_A(1, 0); LOAD_B(1, 0, bfA);
        LGKM; MFMA_Q(0, 0, bfA);
        GBAR;
        if (!last) STAGE(0, 0, 1, 2 * t + 2);
        GBAR;
        LOAD_B(1, 1, bfB);
        LGKM; MFMA_Q(0, 1, bfB);
        GBAR;
        if (!last) STAGE(1, 1, 0, 2 * t + 3);
        GBAR;
        LOAD_A(1, 1);
        LGKM; MFMA_Q(1, 1, bfB);
        GBAR;
        if (!last) STAGE(0, 1, 0, 2 * t + 3);
        GBAR;
        MFMA_Q(1, 0, bfA);
        GBAR;
    }
#undef GBAR
#undef LGKM

    int cr = (lane >> 4) * 4, cc = lane & 15;
#pragma unroll
    for (int i8 = 0; i8 < 8; ++i8) {
        int mh = i8 >> 2, ii = i8 & 3;
        int row0 = bm + mh * 128 + wr * 64 + ii * 16 + cr;
#pragma unroll
        for (int p = 0; p < 4; ++p) {
            short* Cp = C + (size_t)(row0 + p) * N + bn;
#pragma unroll
            for (int j4 = 0; j4 < 4; ++j4) {
                int nh = j4 >> 1, jj = j4 & 1;
                Cp[nh * 128 + wc * 32 + jj * 16 + cc] = f2bf(acc[i8][j4][p]);
            }
        }
    }
}

// -------- 128x128 bf16 GEMM: BK=64, XOR-swizzled LDS, dbuf counted-vmcnt,
// -------- optional split-K (nsk>1: f32 partials at Cv + sk*M*N).
__global__ __launch_bounds__(256) void gemm_bf16_kernel(
    const short* __restrict__ A, const short* __restrict__ W,
    void* __restrict__ Cv, int M, int N, int K,
    const float* __restrict__ bias, int epilogue, int nsk)
{
    __shared__ __align__(16) short As[2][128 * 64];
    __shared__ __align__(16) short Bs[2][128 * 64];
    int tid = threadIdx.x;
    int lane = tid & 63, wv = tid >> 6;
    int nbx = N >> 7;
    int nwg = (M >> 7) * nbx;
    int ntot = nwg * nsk;
    int q = ntot >> 3;
    int wgz = ((int)blockIdx.x & 7) * q + ((int)blockIdx.x >> 3);
    int sk = wgz / nwg;
    int wg = wgz % nwg;
    int bx = wg % nbx, by = wg / nbx;
    int bm = by * 128, bn = bx * 128;
    int wr = wv >> 1, wc = wv & 1;
    int Kl = K / nsk;
    int koff = sk * Kl;

    const int fr = lane & 15;
    const int kl = lane >> 4;
    const int srow = lane >> 3;
    const int schunk = (lane & 7) ^ (srow & 7);

    f32x4 acc[4][4] = {};

    const short* Ab = A + (size_t)bm * K + koff;
    const short* Bb = W + (size_t)bn * K + koff;

    auto STAGE = [&](int buf, int kt) {
        int ko = kt << 6;
#pragma unroll
        for (int s = 0; s < 4; ++s) {
            int row = s * 32 + wv * 8 + srow;
            async16(&As[buf][s * 2048 + wv * 512], Ab + (size_t)row * K + ko + schunk * 8);
            async16(&Bs[buf][s * 2048 + wv * 512], Bb + (size_t)row * K + ko + schunk * 8);
        }
    };

    int NT = Kl >> 6;
    STAGE(0, 0);
    if (NT > 1) STAGE(1, 1);

    for (int t = 0; t < NT; ++t) {
        if (t + 1 < NT) { asm volatile("s_waitcnt vmcnt(8)" ::: "memory"); }
        else            { asm volatile("s_waitcnt vmcnt(0)" ::: "memory"); }
        __builtin_amdgcn_s_barrier();
        __builtin_amdgcn_sched_barrier(0);
        int buf = t & 1;
        short8v af[4][2], bf[4][2];
#pragma unroll
        for (int i = 0; i < 4; ++i) {
            int rl = wr * 64 + i * 16 + fr;
            int rsw = rl & 7;
#pragma unroll
            for (int ks = 0; ks < 2; ++ks)
                af[i][ks] = *(const short8v*)&As[buf][rl * 64 + (((ks * 4 + kl) ^ rsw) * 8)];
        }
#pragma unroll
        for (int j = 0; j < 4; ++j) {
            int rl = wc * 64 + j * 16 + fr;
            int rsw = rl & 7;
#pragma unroll
            for (int ks = 0; ks < 2; ++ks)
                bf[j][ks] = *(const short8v*)&Bs[buf][rl * 64 + (((ks * 4 + kl) ^ rsw) * 8)];
        }
        asm volatile("s_waitcnt lgkmcnt(0)" ::: "memory");
        __builtin_amdgcn_sched_barrier(0);
        __builtin_amdgcn_s_setprio(1);
#pragma unroll
        for (int i = 0; i < 4; ++i)
#pragma unroll
            for (int j = 0; j < 4; ++j)
#pragma unroll
                for (int ks = 0; ks < 2; ++ks)
                    acc[i][j] = __builtin_amdgcn_mfma_f32_16x16x32_bf16(
                        af[i][ks], bf[j][ks], acc[i][j], 0, 0, 0);
        __builtin_amdgcn_s_setprio(0);
        __builtin_amdgcn_s_barrier();
        __builtin_amdgcn_sched_barrier(0);
        if (t + 2 < NT) STAGE(buf, t + 2);
    }

    int cr = (lane >> 4) * 4, cc = lane & 15;
    size_t skoff = (size_t)sk * M * N;
#pragma unroll
    for (int i = 0; i < 4; ++i)
#pragma unroll
        for (int p = 0; p < 4; ++p) {
            int row = bm + wr * 64 + i * 16 + cr + p;
#pragma unroll
            for (int j = 0; j < 4; ++j) {
                int col = bn + wc * 64 + cc + j * 16;
                float v = acc[i][j][p];
                if (epilogue == 2)
                    ((short*)Cv)[(size_t)row * N + col] = f2bf(v);
                else
                    ((float*)Cv)[skoff + (size_t)row * N + col] = v;
            }
        }
}

// ---------------- sum OSK split-K partials -> f32 dst (final layer)
__global__ __launch_bounds__(256) void osum_kernel(
    const float* __restrict__ P, float* __restrict__ out)
{
    size_t i = ((size_t)blockIdx.x * 256 + threadIdx.x) * 4;
    float4 a = *(const float4*)(P + i);
    float4 b = *(const float4*)(P + (size_t)BQ * LQ * D_MODEL + i);
    a.x += b.x; a.y += b.y; a.z += b.z; a.w += b.w;
    *(float4*)(out + i) = a;
}

// ---------- dt_proj: K=64 direct-register MFMA, no LDS, no barriers.
__global__ __launch_bounds__(256) void dtproj_kernel(
    const short* __restrict__ A, const short* __restrict__ W,
    const float* __restrict__ bias, short* __restrict__ Out)
{
    int lane = threadIdx.x & 63, w = threadIdx.x >> 6;
    int m0 = blockIdx.y * 64 + w * 16;
    int bn = blockIdx.x * 128;
    int fr = lane & 15, fk = (lane >> 4) * 8;
    const short* Ap = A + (size_t)(m0 + fr) * DT_RANK + fk;
    short8v a0 = *(const short8v*)(Ap);
    short8v a1 = *(const short8v*)(Ap + 32);
    f32x4 acc[8] = {};
#pragma unroll
    for (int j = 0; j < 8; ++j) {
        const short* Wp = W + (size_t)(bn + j * 16 + fr) * DT_RANK + fk;
        short8v b0 = *(const short8v*)(Wp);
        short8v b1 = *(const short8v*)(Wp + 32);
        acc[j] = __builtin_amdgcn_mfma_f32_16x16x32_bf16(a0, b0, acc[j], 0, 0, 0);
        acc[j] = __builtin_amdgcn_mfma_f32_16x16x32_bf16(a1, b1, acc[j], 0, 0, 0);
    }
    int cr = (lane >> 4) * 4, cc = lane & 15;
#pragma unroll
    for (int j = 0; j < 8; ++j) {
        int col = bn + j * 16 + cc;
        float bv = bias[col];
#pragma unroll
        for (int p = 0; p < 4; ++p) {
            float v = acc[j][p] + bv;
            v = (v > 20.f) ? v : __logf(1.f + __expf(v));
            Out[(size_t)(m0 + cr + p) * D_INNER + col] = f2bf(v);
        }
    }
}

// ------------------------- x_proj: tall-skinny split-K bf16 MFMA, no LDS
__global__ __launch_bounds__(256) void xproj_kernel(
    const short* __restrict__ A, const short* __restrict__ W,
    float* __restrict__ Xpart)
{
    int lane = threadIdx.x & 63, wv = threadIdx.x >> 6;
    int sk = blockIdx.x;
    int m0 = blockIdx.y * 64 + wv * 16;
    int fr = lane & 15, fk = (lane >> 4) * 8;
    const short* Ap = A + (size_t)(m0 + fr) * D_INNER + sk * XKC + fk;
    const short* Wp = W + (size_t)fr * D_INNER + sk * XKC + fk;
    f32x4 acc[6] = {};
    for (int k = 0; k < XKC; k += 32) {
        short8v af = *(const short8v*)(Ap + k);
#pragma unroll
        for (int j = 0; j < 6; ++j) {
            short8v bf = *(const short8v*)(Wp + (size_t)j * 16 * D_INNER + k);
            acc[j] = __builtin_amdgcn_mfma_f32_16x16x32_bf16(af, bf, acc[j], 0, 0, 0);
        }
    }
    int cr = (lane >> 4) * 4, cc = lane & 15;
    float* Op = Xpart + ((size_t)sk * (BQ * LQ) + m0 + cr) * 96 + cc;
#pragma unroll
    for (int j = 0; j < 6; ++j)
#pragma unroll
        for (int p = 0; p < 4; ++p)
            Op[(size_t)p * 96 + j * 16] = acc[j][p];
}

// reduce split-K partials -> xdbl f32; also emit compact bf16 dt_r [BL][64]
__global__ __launch_bounds__(256) void xreduce_kernel(
    const float* __restrict__ Xpart, float* __restrict__ xdbl,
    short* __restrict__ dtr)
{
    size_t i = (size_t)blockIdx.x * 256 + threadIdx.x;
    float s = 0.f;
#pragma unroll
    for (int sk = 0; sk < XSPLITK; ++sk)
        s += Xpart[(size_t)sk * ((size_t)BQ * LQ * 96) + i];
    xdbl[i] = s;
    int col = (int)(i % 96);
    if (col < DT_RANK)
        dtr[(i / 96) * DT_RANK + col] = f2bf(s);
}

// --------------------------- causal conv + SiLU, 2 channels/thread
__global__ __launch_bounds__(256) void conv_silu_kernel(
    const unsigned short* __restrict__ uz, short* __restrict__ outb,
    const float* __restrict__ w, const float* __restrict__ bias)
{
    int idx = blockIdx.x * 256 + threadIdx.x;        // over BLDI/2
    int e0 = idx * 2;
    int c = e0 & (D_INNER - 1);
    int bl = e0 / D_INNER;
    int l = bl & (LQ - 1);
    int b = bl / LQ;
    float acc0 = bias[c], acc1 = bias[c + 1];
    float w0[D_CONV], w1[D_CONV];
#pragma unroll
    for (int k = 0; k < D_CONV; ++k) {
        w0[k] = w[c * D_CONV + k];
        w1[k] = w[(c + 1) * D_CONV + k];
    }
#pragma unroll
    for (int k = 0; k < D_CONV; ++k) {
        int ls = l - (D_CONV - 1) + k;
        if (ls >= 0) {
            unsigned v = *(const unsigned*)&uz[((size_t)b * LQ + ls) * (2 * D_INNER) + c];
            acc0 += bf2f((unsigned short)(v & 0xffff)) * w0[k];
            acc1 += bf2f((unsigned short)(v >> 16)) * w1[k];
        }
    }
    float v0 = acc0 / (1.f + __expf(-acc0));
    float v1 = acc1 / (1.f + __expf(-acc1));
    unsigned o = (unsigned)(unsigned short)f2bf(v0) |
                 ((unsigned)(unsigned short)f2bf(v1) << 16);
    *(unsigned*)&outb[e0] = o;
}

// -------------------------------------------- selective scan, chunked 3-phase
// phase 1: async-LDS-staged u/dt (T14), dA-powers fast path; f32 Fbuf.
__global__ __launch_bounds__(256) void scan_phase1_kernel(
    const unsigned short* __restrict__ u, const unsigned short* __restrict__ dt,
    const float* __restrict__ xdbl, const float* __restrict__ A_log,
    float* __restrict__ dtsumb, float* __restrict__ Fbuf)
{
    __shared__ float S[CHUNK][D_STATE];
    __shared__ __align__(16) unsigned short Ub[2][8][256];
    __shared__ __align__(16) unsigned short Db[2][8][256];
    int t = threadIdx.x;
    int d0 = blockIdx.x * 256;
    int d = d0 + t;
    int c = blockIdx.y;
    int b = blockIdx.z;
    int l0 = c * CHUNK;
    {
        int row = t >> 3, cc2 = (t & 7) * 2;
        const float* src = xdbl + ((size_t)(b * LQ + l0 + row)) * 96 + DT_RANK + cc2;
        *(float2*)&S[row][cc2] = *(const float2*)src;
    }
    const int w = t >> 6, lane = t & 63;
    const int srw = 2 * w + (lane >> 5);
    const int scl = (lane & 31) * 8;
    const unsigned short* ubp = u  + ((size_t)b * LQ + l0) * D_INNER + d0;
    const unsigned short* dbp = dt + ((size_t)b * LQ + l0) * D_INNER + d0;
    auto STAGE1 = [&](int buf, int lb) {
        async16(&Ub[buf][2 * w][0], ubp + (size_t)(lb + srw) * D_INNER + scl);
        async16(&Db[buf][2 * w][0], dbp + (size_t)(lb + srw) * D_INNER + scl);
    };
    STAGE1(0, 0);

    float A[D_STATE], h[D_STATE];
    {
        const float4* ap = (const float4*)(A_log + (size_t)d * D_STATE);
#pragma unroll
        for (int g = 0; g < 4; ++g) {
            float4 a = ap[g];
            A[g*4+0] = -__expf(a.x); A[g*4+1] = -__expf(a.y);
            A[g*4+2] = -__expf(a.z); A[g*4+3] = -__expf(a.w);
        }
    }
    bool pf = true;
#pragma unroll
    for (int n = 1; n < D_STATE; ++n)
        pf = pf && (fabsf(A[n] - (float)(n + 1) * A[0]) <= 1e-4f * (float)(n + 1));
#pragma unroll
    for (int n = 0; n < D_STATE; ++n) h[n] = 0.f;
    float dtsum = 0.f;
    float A0 = A[0];
    asm volatile("s_waitcnt lgkmcnt(0)" ::: "memory");

    for (int bb = 0; bb < CHUNK / 8; ++bb) {
        int buf = bb & 1;
        if (bb + 1 < CHUNK / 8) {
            STAGE1(buf ^ 1, (bb + 1) * 8);
            asm volatile("s_waitcnt vmcnt(2)" ::: "memory");
        } else {
            asm volatile("s_waitcnt vmcnt(0)" ::: "memory");
        }
        __builtin_amdgcn_s_barrier();
        __builtin_amdgcn_sched_barrier(0);
        float uvv[8], dtvv[8];
#pragma unroll
        for (int i = 0; i < 8; ++i) {
            uvv[i]  = bf2f(Ub[buf][i][t]);
            dtvv[i] = bf2f(Db[buf][i][t]);
        }
        if (pf) {
#pragma unroll
            for (int i = 0; i < 8; ++i) {
                int l = bb * 8 + i;
                float dtv = dtvv[i];
                float du = dtv * uvv[i];
                dtsum += dtv;
                float dA[D_STATE];
                dA_powers(__expf(dtv * A0), dA);
#pragma unroll
                for (int n4 = 0; n4 < D_STATE; n4 += 4) {
                    float4 Bv = *(const float4*)&S[l][n4];
                    float bb2[4] = {Bv.x, Bv.y, Bv.z, Bv.w};
#pragma unroll
                    for (int k = 0; k < 4; ++k) {
                        int n = n4 + k;
                        h[n] = dA[n] * h[n] + du * bb2[k];
                    }
                }
            }
        } else {
#pragma unroll
            for (int i = 0; i < 8; ++i) {
                int l = bb * 8 + i;
                float dtv = dtvv[i];
                float du = dtv * uvv[i];
                dtsum += dtv;
#pragma unroll
                for (int n4 = 0; n4 < D_STATE; n4 += 4) {
                    float4 Bv = *(const float4*)&S[l][n4];
                    float bb2[4] = {Bv.x, Bv.y, Bv.z, Bv.w};
#pragma unroll
                    for (int k = 0; k < 4; ++k) {
                        int n = n4 + k;
                        float dA = __expf(dtv * A[n]);
                        h[n] = dA * h[n] + du * bb2[k];
                    }
                }
            }
        }
        __builtin_amdgcn_s_barrier();
        __builtin_amdgcn_sched_barrier(0);
    }
    dtsumb[(size_t)(b * NCHUNK + c) * D_INNER + d] = dtsum;
    size_t base = ((size_t)(b * NCHUNK + c) * D_STATE) * D_INNER + d;
#pragma unroll
    for (int n = 0; n < D_STATE; ++n)
        Fbuf[base + (size_t)n * D_INNER] = h[n];
}

// phase 2: sequential combine; P = exp(A * dtsum) recomputed here
__global__ __launch_bounds__(256) void scan_phase2_kernel(
    const float* __restrict__ dtsumb, const float* __restrict__ A_log,
    float* __restrict__ Fbuf)
{
    int d = blockIdx.x * 256 + threadIdx.x;
    int n = blockIdx.y;
    int b = blockIdx.z;
    float A = -__expf(A_log[(size_t)d * D_STATE + n]);
    float hinit = 0.f;
    for (int c = 0; c < NCHUNK; ++c) {
        size_t idx = ((size_t)(b * NCHUNK + c) * D_STATE + n) * D_INNER + d;
        float F = Fbuf[idx];
        float P = __expf(A * dtsumb[(size_t)(b * NCHUNK + c) * D_INNER + d]);
        Fbuf[idx] = hinit;
        hinit = P * hinit + F;
    }
}

// phase 3: async-LDS-staged u/dt/z (T14), B+C XOR-swizzled, dA-powers,
// fused gate, bf16 out; f32 Hinit.
__global__ __launch_bounds__(256) void scan_phase3_kernel(
    const unsigned short* __restrict__ u, const unsigned short* __restrict__ dt,
    const float* __restrict__ xdbl, const float* __restrict__ A_log,
    const float* __restrict__ Dp, const float* __restrict__ Hinit,
    const unsigned short* __restrict__ uz, short* __restrict__ yout)
{
    __shared__ float S[CHUNK][32];
    __shared__ __align__(16) unsigned short Ub[2][8][256];
    __shared__ __align__(16) unsigned short Db[2][8][256];
    __shared__ __align__(16) unsigned short Zb[2][8][256];
    int t = threadIdx.x;
    int d0 = blockIdx.x * 256;
    int d = d0 + t;
    int c = blockIdx.y;
    int b = blockIdx.z;
    int l0 = c * CHUNK;
    {
        int row = t >> 3, cg = (t & 7) * 4;
        const float* src = xdbl + ((size_t)(b * LQ + l0 + row)) * 96 + DT_RANK + cg;
        *(float4*)&S[row][cg ^ ((row & 7) << 2)] = *(const float4*)src;
    }
    const int w = t >> 6, lane = t & 63;
    const int srw = 2 * w + (lane >> 5);
    const int scl = (lane & 31) * 8;
    const unsigned short* ubp = u  + ((size_t)b * LQ + l0) * D_INNER + d0;
    const unsigned short* dbp = dt + ((size_t)b * LQ + l0) * D_INNER + d0;
    const unsigned short* zbp = uz + ((size_t)b * LQ + l0) * (2 * D_INNER) + D_INNER + d0;
    auto STAGE3 = [&](int buf, int lb) {
        async16(&Ub[buf][2 * w][0], ubp + (size_t)(lb + srw) * D_INNER + scl);
        async16(&Db[buf][2 * w][0], dbp + (size_t)(lb + srw) * D_INNER + scl);
        async16(&Zb[buf][2 * w][0], zbp + (size_t)(lb + srw) * (2 * D_INNER) + scl);
    };
    STAGE3(0, 0);

    float A[D_STATE], h[D_STATE];
    {
        const float4* ap = (const float4*)(A_log + (size_t)d * D_STATE);
#pragma unroll
        for (int g = 0; g < 4; ++g) {
            float4 a = ap[g];
            A[g*4+0] = -__expf(a.x); A[g*4+1] = -__expf(a.y);
            A[g*4+2] = -__expf(a.z); A[g*4+3] = -__expf(a.w);
        }
    }
    bool pf = true;
#pragma unroll
    for (int n = 1; n < D_STATE; ++n)
        pf = pf && (fabsf(A[n] - (float)(n + 1) * A[0]) <= 1e-4f * (float)(n + 1));
    size_t base = ((size_t)(b * NCHUNK + c) * D_STATE) * D_INNER + d;
#pragma unroll
    for (int n = 0; n < D_STATE; ++n)
        h[n] = Hinit[base + (size_t)n * D_INNER];
    float Dd = Dp[d];
    float A0 = A[0];
    short* yp = yout + ((size_t)b * LQ + l0) * D_INNER + d;
    asm volatile("s_waitcnt lgkmcnt(0)" ::: "memory");

    for (int bb = 0; bb < CHUNK / 8; ++bb) {
        int buf = bb & 1;
        if (bb + 1 < CHUNK / 8) {
            STAGE3(buf ^ 1, (bb + 1) * 8);
            asm volatile("s_waitcnt vmcnt(3)" ::: "memory");
        } else {
            asm volatile("s_waitcnt vmcnt(0)" ::: "memory");
        }
        __builtin_amdgcn_s_barrier();
        __builtin_amdgcn_sched_barrier(0);
        float uvv[8], dtvv[8], zvv[8];
#pragma unroll
        for (int i = 0; i < 8; ++i) {
            uvv[i]  = bf2f(Ub[buf][i][t]);
            dtvv[i] = bf2f(Db[buf][i][t]);
            zvv[i]  = bf2f(Zb[buf][i][t]);
        }
        if (pf) {
#pragma unroll
            for (int i = 0; i < 8; ++i) {
                int l = bb * 8 + i;
                float dtv = dtvv[i];
                float du = dtv * uvv[i];
                float acc = 0.f;
                int sw = (l & 7) << 2;
                float dA[D_STATE];
                dA_powers(__expf(dtv * A0), dA);
#pragma unroll
                for (int n4 = 0; n4 < D_STATE; n4 += 4) {
                    float4 Bv = *(const float4*)&S[l][n4 ^ sw];
                    float4 Cv = *(const float4*)&S[l][(16 + n4) ^ sw];
                    float bb2[4] = {Bv.x, Bv.y, Bv.z, Bv.w};
                    float cc2[4] = {Cv.x, Cv.y, Cv.z, Cv.w};
#pragma unroll
                    for (int k = 0; k < 4; ++k) {
                        int n = n4 + k;
                        h[n] = dA[n] * h[n] + du * bb2[k];
                        acc += h[n] * cc2[k];
                    }
                }
                float y = acc + uvv[i] * Dd;
                float zv = zvv[i];
                float g = zv / (1.f + __expf(-zv));
                yp[(size_t)l * D_INNER] = f2bf(y * g);
            }
        } else {
#pragma unroll
            for (int i = 0; i < 8; ++i) {
                int l = bb * 8 + i;
                float dtv = dtvv[i];
                float du = dtv * uvv[i];
                float acc = 0.f;
                int sw = (l & 7) << 2;
#pragma unroll
                for (int n4 = 0; n4 < D_STATE; n4 += 4) {
                    float4 Bv = *(const float4*)&S[l][n4 ^ sw];
                    float4 Cv = *(const float4*)&S[l][(16 + n4) ^ sw];
                    float bb2[4] = {Bv.x, Bv.y, Bv.z, Bv.w};
                    float cc2[4] = {Cv.x, Cv.y, Cv.z, Cv.w};
#pragma unroll
                    for (int k = 0; k < 4; ++k) {
                        int n = n4 + k;
                        float dA = __expf(dtv * A[n]);
                        h[n] = dA * h[n] + du * bb2[k];
                        acc += h[n] * cc2[k];
                    }
                }
                float y = acc + uvv[i] * Dd;
                float zv = zvv[i];
                float g = zv / (1.f + __expf(-zv));
                yp[(size_t)l * D_INNER] = f2bf(y * g);
            }
        }
        __builtin_amdgcn_s_barrier();
        __builtin_amdgcn_sched_barrier(0);
    }
}

// --------------- all 4 weight tensors -> bf16 in ONE launch
__global__ __launch_bounds__(256) void convert_all_kernel(
    const float* __restrict__ w_in, const float* __restrict__ w_out,
    const float* __restrict__ w_xp, const float* __restrict__ w_dt,
    short* __restrict__ wbuf)
{
    const int IN_B  = (2 * D_INNER * D_MODEL) / 1024;
    const int OUT_B = (D_MODEL * D_INNER) / 1024;
    const int XP_B  = (96 * D_INNER) / 1024;
    int blk = blockIdx.x;
    const float* src; short* dst;
    if (blk < IN_B)                 { src = w_in;  dst = wbuf; }
    else if (blk < IN_B + OUT_B)    { src = w_out; dst = wbuf + 2 * D_INNER * D_MODEL; blk -= IN_B; }
    else if (blk < IN_B + OUT_B + XP_B) { src = w_xp; dst = wbuf + 2 * D_INNER * D_MODEL + D_MODEL * D_INNER; blk -= IN_B + OUT_B; }
    else { src = w_dt; dst = wbuf + 2 * D_INNER * D_MODEL + D_MODEL * D_INNER + 96 * D_INNER; blk -= IN_B + OUT_B + XP_B; }
    int i = blk * 1024 + threadIdx.x * 4;
    float4 v = *(const float4*)(src + i);
    short4 o = make_short4(f2bf(v.x), f2bf(v.y), f2bf(v.z), f2bf(v.w));
    *(short4*)(dst + i) = o;
}

// ---------------------------------------------------------------- launcher
extern "C" void kernel_launch(void* const* d_in, const int* in_sizes, int n_in,
                              void* d_out, int out_size, void* d_ws, size_t ws_size,
                              hipStream_t stream)
{
    const float* x        = (const float*)d_in[0];
    const float* norm_w   = (const float*)d_in[2];
    const float* norm_b   = (const float*)d_in[3];
    const float* in_proj  = (const float*)d_in[4];
    const float* conv_w   = (const float*)d_in[5];
    const float* conv_b   = (const float*)d_in[6];
    const float* x_proj   = (const float*)d_in[7];
    const float* dt_proj  = (const float*)d_in[8];
    const float* dt_projb = (const float*)d_in[9];
    const float* A_log    = (const float*)d_in[10];
    const float* Dp       = (const float*)d_in[11];
    const float* out_proj = (const float*)d_in[12];
    float* out = (float*)d_out;
    float* ws  = (float*)d_ws;

    const size_t BL   = (size_t)BQ * LQ;            // 4096
    const size_t BLDM = BL * D_MODEL;
    const size_t BLDI = BL * D_INNER;
    const int IN_W  = 2 * D_INNER * D_MODEL;
    const int OUT_W = D_MODEL * D_INNER;
    const int XP_W  = 96 * D_INNER;
    const int DT_W  = D_INNER * DT_RANK;
    const int CV_BLOCKS = (IN_W + OUT_W + XP_W + DT_W) / 1024;

    size_t o = 0;
    short* hnb   = (short*)(ws + o); o += BLDM / 2;
    short* uzb   = (short*)(ws + o); o += BL * 2 * D_INNER / 2;
    short* dtb   = (short*)(ws + o); o += BLDI / 2;
    float* xdbl  = ws + o; o += BL * 96;
    float* Xpart = ws + o; o += (size_t)XSPLITK * BL * 96;
    float* Fbuf  = ws + o; o += (size_t)BQ * NCHUNK * D_STATE * D_INNER;
    float* dtsumb = ws + o; o += (size_t)BQ * NCHUNK * D_INNER;
    short* ucx   = (short*)(ws + o); o += BLDI / 2;
    short* dtr   = (short*)(ws + o); o += BL * DT_RANK / 2;
    float* Opart = ws + o; o += (size_t)OSK * BLDM;
    short* wbuf  = (short*)(ws + o);
    o += (size_t)(IN_W + OUT_W + XP_W + DT_W + 1) / 2;

    for (int layer = 0; layer < DEPTH; ++layer) {
        if (layer == 0)
            layernorm_kernel<<<(int)BL, 256, 0, stream>>>(
                x, norm_w, norm_b, hnb);

        convert_all_kernel<<<CV_BLOCKS, 256, 0, stream>>>(
            in_proj + (size_t)layer * IN_W, out_proj + (size_t)layer * OUT_W,
            x_proj + (size_t)layer * XP_W, dt_proj + (size_t)layer * DT_W, wbuf);

        gemm256_bf16_kernel<<<(int)(BL / 256) * (2 * D_INNER / 256), 512, 0, stream>>>(
            hnb, wbuf, uzb, (int)BL, 2 * D_INNER, D_MODEL);

        conv_silu_kernel<<<(int)(BLDI / 512), 256, 0, stream>>>(
            (const unsigned short*)uzb, ucx,
            conv_w + (size_t)layer * D_INNER * D_CONV,
            conv_b + (size_t)layer * D_INNER);

        xproj_kernel<<<dim3(XSPLITK, BL / 64), 256, 0, stream>>>(
            ucx, wbuf + IN_W + OUT_W, Xpart);
        xreduce_kernel<<<(int)(BL * 96 / 256), 256, 0, stream>>>(Xpart, xdbl, dtr);

        dtproj_kernel<<<dim3(D_INNER / 128, BL / 64), 256, 0, stream>>>(
            dtr, wbuf + IN_W + OUT_W + XP_W,
            dt_projb + (size_t)layer * D_INNER, dtb);

        const float* Al = A_log + (size_t)layer * D_INNER * D_STATE;
        scan_phase1_kernel<<<dim3(D_INNER / 256, NCHUNK, BQ), 256, 0, stream>>>(
            (const unsigned short*)ucx, (const unsigned short*)dtb, xdbl, Al,
            dtsumb, Fbuf);
        scan_phase2_kernel<<<dim3(D_INNER / 256, D_STATE, BQ), 256, 0, stream>>>(
            dtsumb, Al, Fbuf);
        scan_phase3_kernel<<<dim3(D_INNER / 256, NCHUNK, BQ), 256, 0, stream>>>(
            (const unsigned short*)ucx, (const unsigned short*)dtb, xdbl, Al,
            Dp + (size_t)layer * D_INNER, Fbuf,
            (const unsigned short*)uzb, (short*)ucx);

        gemm_bf16_kernel<<<(int)(BL / 128) * (D_MODEL / 128) * OSK, 256, 0, stream>>>(
            ucx, wbuf + IN_W, Opart, (int)BL, D_MODEL, D_INNER, nullptr, 0, OSK);

        if (layer == DEPTH - 1)
            osum_kernel<<<(int)(BLDM / 1024), 256, 0, stream>>>(Opart, out);
        else
            osum_ln_kernel<<<(int)BL, 256, 0, stream>>>(
                Opart, norm_w + (size_t)(layer + 1) * D_MODEL,
                norm_b + (size_t)(layer + 1) * D_MODEL, hnb);
    }
}